// Round 5
// baseline (874.937 us; speedup 1.0000x reference)
//
#include <hip/hip_runtime.h>

#define NN 100000
#define EE 600000
#define HH 128
#define GG 1000
#define NPAD 100096   // 1564 * 64
#define NBLK2 1564

typedef __attribute__((ext_vector_type(8))) short bf16x8;
typedef __attribute__((ext_vector_type(4))) float f32x4;

__device__ inline short f2bf(float x){
    unsigned u = __float_as_uint(x);
    unsigned r = (u + 0x7FFFu + ((u >> 16) & 1u)) >> 16;
    return (short)r;
}
__device__ inline float bf2f(short h){
    unsigned u = ((unsigned)(unsigned short)h) << 16;
    return __uint_as_float(u);
}

// ---------------- CSR build ----------------
__global__ void k_zero_i32(int* __restrict__ p, int n){
    int i = blockIdx.x*256 + threadIdx.x;
    if (i < n) p[i] = 0;
}

__global__ void k_hist(const int* __restrict__ dst, int* __restrict__ cnt){
    int e = blockIdx.x*256 + threadIdx.x;
    if (e < EE) atomicAdd(&cnt[dst[e]], 1);
}

__global__ void k_scan1(const int* __restrict__ cnt, int* __restrict__ excl,
                        int* __restrict__ bsums, int n){
    __shared__ int wsum[4];
    int t = threadIdx.x;
    int idx = blockIdx.x*1024 + t*4;
    int c[4];
#pragma unroll
    for (int i = 0; i < 4; i++) c[i] = (idx+i < n) ? cnt[idx+i] : 0;
    int s = c[0]+c[1]+c[2]+c[3];
    int lane = t & 63, w = t >> 6;
    int x = s;
#pragma unroll
    for (int off = 1; off < 64; off <<= 1){
        int y = __shfl_up(x, off);
        if (lane >= off) x += y;
    }
    if (lane == 63) wsum[w] = x;
    __syncthreads();
    int woff = 0;
    for (int i = 0; i < w; i++) woff += wsum[i];
    int run = woff + x - s;
#pragma unroll
    for (int i = 0; i < 4; i++){
        if (idx+i < n) excl[idx+i] = run;
        run += c[i];
    }
    if (t == 255) bsums[blockIdx.x] = woff + x;
}

__global__ void k_scan2(int* __restrict__ bsums, int nb){
    __shared__ int ws2[2];
    int t = threadIdx.x;
    int v = (t < nb) ? bsums[t] : 0;
    int lane = t & 63, w = t >> 6;
    int x = v;
#pragma unroll
    for (int off = 1; off < 64; off <<= 1){
        int y = __shfl_up(x, off);
        if (lane >= off) x += y;
    }
    if (lane == 63) ws2[w] = x;
    __syncthreads();
    int off0 = (w == 1) ? ws2[0] : 0;
    if (t < nb) bsums[t] = off0 + x - v;
}

__global__ void k_scan3(int* __restrict__ rp, const int* __restrict__ bsums,
                        int* __restrict__ fill, int n){
    int i = blockIdx.x*256 + threadIdx.x;
    if (i < n){
        int r = rp[i] + bsums[i >> 10];
        rp[i] = r;
        fill[i] = r;
    }
    if (i == 0) rp[n] = EE;
}

__global__ void k_place(const int* __restrict__ src, const int* __restrict__ dst,
                        int* __restrict__ fill, int* __restrict__ ssrc){
    int e = blockIdx.x*256 + threadIdx.x;
    if (e < EE){
        int p = atomicAdd(&fill[dst[e]], 1);
        ssrc[p] = src[e];
    }
}

// ---------------- graph rowptr from sorted batch ----------------
__global__ void k_bounds(const int* __restrict__ batch, int* __restrict__ rp_g){
    int i = blockIdx.x*256 + threadIdx.x;
    if (i >= NN) return;
    int b = batch[i];
    if (i == 0){
        for (int g = 0; g <= b; g++) rp_g[g] = 0;
    } else {
        int p = batch[i-1];
        for (int g = p+1; g <= b; g++) rp_g[g] = i;
    }
    if (i == NN-1){
        for (int g = b+1; g <= GG; g++) rp_g[g] = NN;
    }
}

// ---------------- W pre-swizzle into bf16 hi/lo B-fragment order ----------
// frag(kc, ct, l) at ((kc*8 + ct)*64 + l)*8 + j ; value W[kc*32+(l>>4)*8+j][ct*16+(l&15)]
__global__ void k_wprep(const float* __restrict__ W2_0, const float* __restrict__ W1s,
                        const float* __restrict__ W2s, short* __restrict__ Wp){
    int tid = blockIdx.x*256 + threadIdx.x;
    if (tid >= 9*16384) return;
    int m = tid >> 14;
    int r = tid & 16383;
    int j = r & 7, l = (r >> 3) & 63, ctkc = r >> 9;
    int ct = ctkc & 7, kc = ctkc >> 3;
    int k = kc*32 + ((l >> 4) << 3) + j;
    int n = (ct << 4) + (l & 15);
    const float* W = (m == 0) ? W2_0
                   : (m <= 4) ? (W1s + (size_t)(m-1)*HH*HH)
                              : (W2s + (size_t)(m-5)*HH*HH);
    float w = W[k*HH + n];
    short hi = f2bf(w);
    short lo = f2bf(w - bf2f(hi));
    short* base = Wp + (size_t)m*32768;
    base[r] = hi;
    base[16384 + r] = lo;
}

// ---------------- layer 0 (in=3) ----------------
__global__ void k_agg3(const float* __restrict__ x, const int* __restrict__ rp,
                       const int* __restrict__ ssrc, float* __restrict__ y){
    int i = blockIdx.x*256 + threadIdx.x;
    if (i >= NN) return;
    float a0 = x[3*i], a1 = x[3*i+1], a2 = x[3*i+2];
    int b = rp[i], e = rp[i+1];
    for (int k = b; k < e; k++){
        int s = ssrc[k];
        a0 += x[3*s]; a1 += x[3*s+1]; a2 += x[3*s+2];
    }
    y[3*i] = a0; y[3*i+1] = a1; y[3*i+2] = a2;
}

__global__ void k_mlp0(const float* __restrict__ y0, const float* __restrict__ W1,
                       const float* __restrict__ b1, const float* __restrict__ g,
                       const float* __restrict__ be, const float* __restrict__ m,
                       const float* __restrict__ v, float* __restrict__ out){
    int idx = blockIdx.x*256 + threadIdx.x;
    if (idx >= NN*HH) return;
    int i = idx >> 7, j = idx & 127;
    float acc = b1[j] + y0[3*i]*W1[j] + y0[3*i+1]*W1[HH+j] + y0[3*i+2]*W1[2*HH+j];
    float r = rsqrtf(v[j] + 1e-5f);
    acc = g[j]*(acc - m[j])*r + be[j];
    out[idx] = fmaxf(acc, 0.f);
}

// ---------------- fused [agg?]+GEMM: out = relu(BN(agg(A) @ W + b)) ------------
// 128 threads, 64-row tile. Phase 1: gather/stream rows (coalesced 512B row
// loads), trunc-split to bf16 hi/lo, store to LDS in MFMA-fragment order
// (element (r,c): tile=r>>4, m=r&15, kc=c>>5, q=(c>>3)&3, j=c&7 at
//  ((tile*4+kc)*64 + ((q*16+m)^kc))*8 + j ; XOR-kc breaks write-bank aliasing).
// Phase 2: lane-contiguous ds b128 frag reads + bf16x3 MFMA.
__global__ __launch_bounds__(128, 4)
void k_gemm2(const float* __restrict__ A, const int* __restrict__ rp,
             const int* __restrict__ ssrc, const short* __restrict__ Wp,
             const float* __restrict__ bias, const float* __restrict__ g,
             const float* __restrict__ be, const float* __restrict__ m,
             const float* __restrict__ v, int use_bn,
             float* __restrict__ out){
    __shared__ short sAh[8192];
    __shared__ short sAl[8192];
    const int t = threadIdx.x;
    const int R0 = blockIdx.x * 64;

    // ---- phase 1 ----
    {
        int hw = t >> 5, ln = t & 31;
        int c4 = ln << 2;
        int kc1 = c4 >> 5, q1 = (c4 >> 3) & 3, j1 = c4 & 7;
        const float* Ac = A + c4;
        for (int r = hw; r < 64; r += 4){
            int node = R0 + r;
            float4 a0 = *(const float4*)&Ac[(size_t)node*HH];
            if (rp && node < NN){
                int b = rp[node], e = rp[node+1];
                float4 a1 = {0,0,0,0}, a2 = {0,0,0,0}, a3 = {0,0,0,0};
                int k = b;
                for (; k + 3 < e; k += 4){
                    int s0 = ssrc[k], s1 = ssrc[k+1], s2 = ssrc[k+2], s3 = ssrc[k+3];
                    float4 t0 = *(const float4*)&Ac[(size_t)s0*HH];
                    float4 t1 = *(const float4*)&Ac[(size_t)s1*HH];
                    float4 t2 = *(const float4*)&Ac[(size_t)s2*HH];
                    float4 t3 = *(const float4*)&Ac[(size_t)s3*HH];
                    a0.x+=t0.x; a0.y+=t0.y; a0.z+=t0.z; a0.w+=t0.w;
                    a1.x+=t1.x; a1.y+=t1.y; a1.z+=t1.z; a1.w+=t1.w;
                    a2.x+=t2.x; a2.y+=t2.y; a2.z+=t2.z; a2.w+=t2.w;
                    a3.x+=t3.x; a3.y+=t3.y; a3.z+=t3.z; a3.w+=t3.w;
                }
                if (k + 1 < e){
                    int s0 = ssrc[k], s1 = ssrc[k+1];
                    float4 t0 = *(const float4*)&Ac[(size_t)s0*HH];
                    float4 t1 = *(const float4*)&Ac[(size_t)s1*HH];
                    a0.x+=t0.x; a0.y+=t0.y; a0.z+=t0.z; a0.w+=t0.w;
                    a1.x+=t1.x; a1.y+=t1.y; a1.z+=t1.z; a1.w+=t1.w;
                    k += 2;
                }
                if (k < e){
                    int s0 = ssrc[k];
                    float4 t0 = *(const float4*)&Ac[(size_t)s0*HH];
                    a0.x+=t0.x; a0.y+=t0.y; a0.z+=t0.z; a0.w+=t0.w;
                }
                a0.x += a1.x+a2.x+a3.x; a0.y += a1.y+a2.y+a3.y;
                a0.z += a1.z+a2.z+a3.z; a0.w += a1.w+a2.w+a3.w;
            }
            int tile = r >> 4, mm = r & 15;
            int chunk = ((q1 << 4) + mm) ^ kc1;
            int pos = (((tile << 2) + kc1)*64 + chunk)*8 + j1;
            float xs[4] = {a0.x, a0.y, a0.z, a0.w};
            unsigned hp[2], lp[2];
#pragma unroll
            for (int i = 0; i < 2; i++){
                unsigned u0 = __float_as_uint(xs[2*i]);
                unsigned u1 = __float_as_uint(xs[2*i+1]);
                float r0 = xs[2*i]   - __uint_as_float(u0 & 0xFFFF0000u);
                float r1 = xs[2*i+1] - __uint_as_float(u1 & 0xFFFF0000u);
                hp[i] = (u0 >> 16) | (u1 & 0xFFFF0000u);
                lp[i] = (__float_as_uint(r0) >> 16) | (__float_as_uint(r1) & 0xFFFF0000u);
            }
            *(uint2*)&sAh[pos] = make_uint2(hp[0], hp[1]);
            *(uint2*)&sAl[pos] = make_uint2(lp[0], lp[1]);
        }
    }
    __syncthreads();

    // ---- phase 2 ----
    const int w = t >> 6, l = t & 63;
    const int n = l & 15, q = l >> 4;
    const short* Wh = Wp;
    const short* Wl = Wp + 16384;

    f32x4 acc[2][8];
#pragma unroll
    for (int rt = 0; rt < 2; rt++)
#pragma unroll
        for (int ct = 0; ct < 8; ct++) acc[rt][ct] = (f32x4){0.f,0.f,0.f,0.f};

#pragma unroll
    for (int kc = 0; kc < 4; kc++){
        int lx = l ^ kc;
        int p0 = (((w*2 + 0)*4 + kc)*64 + lx)*8;
        int p1 = (((w*2 + 1)*4 + kc)*64 + lx)*8;
        bf16x8 ah0 = *(const bf16x8*)&sAh[p0];
        bf16x8 al0 = *(const bf16x8*)&sAl[p0];
        bf16x8 ah1 = *(const bf16x8*)&sAh[p1];
        bf16x8 al1 = *(const bf16x8*)&sAl[p1];
        const short* ph = Wh + (size_t)(kc*8)*512 + l*8;
        const short* pl = Wl + (size_t)(kc*8)*512 + l*8;
#pragma unroll
        for (int ct = 0; ct < 8; ct++){
            bf16x8 bh = *(const bf16x8*)(ph + ct*512);
            bf16x8 bl = *(const bf16x8*)(pl + ct*512);
            acc[0][ct] = __builtin_amdgcn_mfma_f32_16x16x32_bf16(ah0, bh, acc[0][ct], 0, 0, 0);
            acc[1][ct] = __builtin_amdgcn_mfma_f32_16x16x32_bf16(ah1, bh, acc[1][ct], 0, 0, 0);
            acc[0][ct] = __builtin_amdgcn_mfma_f32_16x16x32_bf16(al0, bh, acc[0][ct], 0, 0, 0);
            acc[1][ct] = __builtin_amdgcn_mfma_f32_16x16x32_bf16(al1, bh, acc[1][ct], 0, 0, 0);
            acc[0][ct] = __builtin_amdgcn_mfma_f32_16x16x32_bf16(ah0, bl, acc[0][ct], 0, 0, 0);
            acc[1][ct] = __builtin_amdgcn_mfma_f32_16x16x32_bf16(ah1, bl, acc[1][ct], 0, 0, 0);
        }
    }

    // ---- epilogue: out = relu(sc*acc + sh) ----
#pragma unroll
    for (int ct = 0; ct < 8; ct++){
        int j = (ct << 4) + n;
        float scv, shv;
        if (use_bn){
            float rr = rsqrtf(v[j] + 1e-5f);
            float gg = g[j]*rr;
            scv = gg;
            shv = be[j] + gg*(bias[j] - m[j]);
        } else {
            scv = 1.f;
            shv = bias[j];
        }
#pragma unroll
        for (int rt = 0; rt < 2; rt++){
#pragma unroll
            for (int r = 0; r < 4; r++){
                int row = R0 + w*32 + rt*16 + q*4 + r;
                out[(size_t)row*HH + j] = fmaxf(fmaf(acc[rt][ct][r], scv, shv), 0.f);
            }
        }
    }
}

// ---------------- pooling + classifier: block per graph, no atomics ---------
__global__ void k_pool2(const float* __restrict__ h, const float* __restrict__ Wc,
                        const float* __restrict__ bc, const int* __restrict__ rp_g,
                        float* __restrict__ out){
    __shared__ float ws[4];
    int g = blockIdx.x, t = threadIdx.x;
    long beg = (long)rp_g[g]*HH, end = (long)rp_g[g+1]*HH;
    float s = 0.f;
    for (long i = beg + t; i < end; i += 256) s += h[i]*Wc[(int)(i & 127)];
    int lane = t & 63, w = t >> 6;
#pragma unroll
    for (int off = 32; off > 0; off >>= 1) s += __shfl_down(s, off);
    if (lane == 0) ws[w] = s;
    __syncthreads();
    if (t == 0) out[g] = bc[0] + ws[0] + ws[1] + ws[2] + ws[3];
}

extern "C" void kernel_launch(void* const* d_in, const int* in_sizes, int n_in,
                              void* d_out, int out_size, void* d_ws, size_t ws_size,
                              hipStream_t stream){
    const float* x     = (const float*)d_in[0];
    const int*   ei    = (const int*)d_in[1];
    const int*   batch = (const int*)d_in[2];
    const float* W1_0  = (const float*)d_in[3];
    const float* b1_0  = (const float*)d_in[4];
    const float* g_0   = (const float*)d_in[5];
    const float* be_0  = (const float*)d_in[6];
    const float* m_0   = (const float*)d_in[7];
    const float* v_0   = (const float*)d_in[8];
    const float* W2_0  = (const float*)d_in[9];
    const float* b2_0  = (const float*)d_in[10];
    const float* W1s   = (const float*)d_in[11];
    const float* b1s   = (const float*)d_in[12];
    const float* gs    = (const float*)d_in[13];
    const float* bes   = (const float*)d_in[14];
    const float* ms    = (const float*)d_in[15];
    const float* vs    = (const float*)d_in[16];
    const float* W2s   = (const float*)d_in[17];
    const float* b2s   = (const float*)d_in[18];
    const float* Wc    = (const float*)d_in[19];
    const float* bc    = (const float*)d_in[20];

    float* P0 = (float*)d_ws;
    float* P1 = P0 + (size_t)NPAD*HH;
    int* rp    = (int*)(P1 + (size_t)NPAD*HH);
    int* fill  = rp + (NN + 1);
    int* ssrc  = fill + NN;
    int* bsums = ssrc + EE;
    int* rp_g  = bsums + 128;
    size_t wp_off = (size_t)(rp_g + (GG + 1) - (int*)d_ws);
    wp_off = (wp_off + 3) & ~(size_t)3;
    short* Wp = (short*)((int*)d_ws + wp_off);

    const int* src = ei;
    const int* dst = ei + EE;

    // --- CSR build ---
    k_zero_i32<<<(NN+255)/256, 256, 0, stream>>>(fill, NN);
    k_hist<<<(EE+255)/256, 256, 0, stream>>>(dst, fill);
    k_scan1<<<98, 256, 0, stream>>>(fill, rp, bsums, NN);
    k_scan2<<<1, 128, 0, stream>>>(bsums, 98);
    k_scan3<<<(NN+255)/256, 256, 0, stream>>>(rp, bsums, fill, NN);
    k_place<<<(EE+255)/256, 256, 0, stream>>>(src, dst, fill, ssrc);

    // --- graph rowptr + weight pre-swizzle ---
    k_bounds<<<(NN+255)/256, 256, 0, stream>>>(batch, rp_g);
    k_wprep<<<(9*16384)/256, 256, 0, stream>>>(W2_0, W1s, W2s, Wp);

    // --- layer 0 (in=3) ---
    k_agg3<<<(NN+255)/256, 256, 0, stream>>>(x, rp, ssrc, P0);
    k_mlp0<<<(NN*HH)/256, 256, 0, stream>>>(P0, W1_0, b1_0, g_0, be_0, m_0, v_0, P1);
    k_gemm2<<<NBLK2, 128, 0, stream>>>(P1, nullptr, nullptr, Wp, b2_0,
                                       nullptr, nullptr, nullptr, nullptr, 0, P0);

    // --- layers 1..4: fused(agg+GEMM1) then plain GEMM2 ---
    for (int l = 0; l < 4; l++){
        k_gemm2<<<NBLK2, 128, 0, stream>>>(P0, rp, ssrc, Wp + (size_t)(1+l)*32768,
                                           b1s + l*HH, gs + l*HH, bes + l*HH,
                                           ms + l*HH, vs + l*HH, 1, P1);
        k_gemm2<<<NBLK2, 128, 0, stream>>>(P1, nullptr, nullptr, Wp + (size_t)(5+l)*32768,
                                           b2s + l*HH, nullptr, nullptr, nullptr, nullptr,
                                           0, P0);
    }

    // --- pooling + classifier (no atomics) ---
    k_pool2<<<GG, 256, 0, stream>>>(P0, Wc, bc, rp_g, (float*)d_out);
}

// Round 6
// 709.682 us; speedup vs baseline: 1.2329x; 1.2329x over previous
//
#include <hip/hip_runtime.h>

#define NN 100000
#define EE 600000
#define HH 128
#define GG 1000
#define NPAD 100096   // 1564 * 64
#define NBLK2 1564

typedef __attribute__((ext_vector_type(8))) short bf16x8;
typedef __attribute__((ext_vector_type(4))) float f32x4;

__device__ inline short f2bf(float x){
    unsigned u = __float_as_uint(x);
    unsigned r = (u + 0x7FFFu + ((u >> 16) & 1u)) >> 16;
    return (short)r;
}
__device__ inline float bf2f(short h){
    unsigned u = ((unsigned)(unsigned short)h) << 16;
    return __uint_as_float(u);
}

// ---------------- CSR build ----------------
__global__ void k_zero_i32(int* __restrict__ p, int n){
    int i = blockIdx.x*256 + threadIdx.x;
    if (i < n) p[i] = 0;
}

__global__ void k_hist(const int* __restrict__ dst, int* __restrict__ cnt){
    int e = blockIdx.x*256 + threadIdx.x;
    if (e < EE) atomicAdd(&cnt[dst[e]], 1);
}

__global__ void k_scan1(const int* __restrict__ cnt, int* __restrict__ excl,
                        int* __restrict__ bsums, int n){
    __shared__ int wsum[4];
    int t = threadIdx.x;
    int idx = blockIdx.x*1024 + t*4;
    int c[4];
#pragma unroll
    for (int i = 0; i < 4; i++) c[i] = (idx+i < n) ? cnt[idx+i] : 0;
    int s = c[0]+c[1]+c[2]+c[3];
    int lane = t & 63, w = t >> 6;
    int x = s;
#pragma unroll
    for (int off = 1; off < 64; off <<= 1){
        int y = __shfl_up(x, off);
        if (lane >= off) x += y;
    }
    if (lane == 63) wsum[w] = x;
    __syncthreads();
    int woff = 0;
    for (int i = 0; i < w; i++) woff += wsum[i];
    int run = woff + x - s;
#pragma unroll
    for (int i = 0; i < 4; i++){
        if (idx+i < n) excl[idx+i] = run;
        run += c[i];
    }
    if (t == 255) bsums[blockIdx.x] = woff + x;
}

__global__ void k_scan2(int* __restrict__ bsums, int nb){
    __shared__ int ws2[2];
    int t = threadIdx.x;
    int v = (t < nb) ? bsums[t] : 0;
    int lane = t & 63, w = t >> 6;
    int x = v;
#pragma unroll
    for (int off = 1; off < 64; off <<= 1){
        int y = __shfl_up(x, off);
        if (lane >= off) x += y;
    }
    if (lane == 63) ws2[w] = x;
    __syncthreads();
    int off0 = (w == 1) ? ws2[0] : 0;
    if (t < nb) bsums[t] = off0 + x - v;
}

__global__ void k_scan3(int* __restrict__ rp, const int* __restrict__ bsums,
                        int* __restrict__ fill, int n){
    int i = blockIdx.x*256 + threadIdx.x;
    if (i < n){
        int r = rp[i] + bsums[i >> 10];
        rp[i] = r;
        fill[i] = r;
    }
    if (i == 0) rp[n] = EE;
}

__global__ void k_place(const int* __restrict__ src, const int* __restrict__ dst,
                        int* __restrict__ fill, int* __restrict__ ssrc){
    int e = blockIdx.x*256 + threadIdx.x;
    if (e < EE){
        int p = atomicAdd(&fill[dst[e]], 1);
        ssrc[p] = src[e];
    }
}

// ---------------- graph rowptr from sorted batch ----------------
__global__ void k_bounds(const int* __restrict__ batch, int* __restrict__ rp_g){
    int i = blockIdx.x*256 + threadIdx.x;
    if (i >= NN) return;
    int b = batch[i];
    if (i == 0){
        for (int g = 0; g <= b; g++) rp_g[g] = 0;
    } else {
        int p = batch[i-1];
        for (int g = p+1; g <= b; g++) rp_g[g] = i;
    }
    if (i == NN-1){
        for (int g = b+1; g <= GG; g++) rp_g[g] = NN;
    }
}

// ---------------- W pre-swizzle into bf16 hi/lo B-fragment order ----------
// frag(kc, ct, l) at ((kc*8 + ct)*64 + l)*8 + j ; value W[kc*32+(l>>4)*8+j][ct*16+(l&15)]
__global__ void k_wprep(const float* __restrict__ W2_0, const float* __restrict__ W1s,
                        const float* __restrict__ W2s, short* __restrict__ Wp){
    int tid = blockIdx.x*256 + threadIdx.x;
    if (tid >= 9*16384) return;
    int m = tid >> 14;
    int r = tid & 16383;
    int j = r & 7, l = (r >> 3) & 63, ctkc = r >> 9;
    int ct = ctkc & 7, kc = ctkc >> 3;
    int k = kc*32 + ((l >> 4) << 3) + j;
    int n = (ct << 4) + (l & 15);
    const float* W = (m == 0) ? W2_0
                   : (m <= 4) ? (W1s + (size_t)(m-1)*HH*HH)
                              : (W2s + (size_t)(m-5)*HH*HH);
    float w = W[k*HH + n];
    short hi = f2bf(w);
    short lo = f2bf(w - bf2f(hi));
    short* base = Wp + (size_t)m*32768;
    base[r] = hi;
    base[16384 + r] = lo;
}

// ---------------- layer 0 (in=3) ----------------
__global__ void k_agg3(const float* __restrict__ x, const int* __restrict__ rp,
                       const int* __restrict__ ssrc, float* __restrict__ y){
    int i = blockIdx.x*256 + threadIdx.x;
    if (i >= NN) return;
    float a0 = x[3*i], a1 = x[3*i+1], a2 = x[3*i+2];
    int b = rp[i], e = rp[i+1];
    for (int k = b; k < e; k++){
        int s = ssrc[k];
        a0 += x[3*s]; a1 += x[3*s+1]; a2 += x[3*s+2];
    }
    y[3*i] = a0; y[3*i+1] = a1; y[3*i+2] = a2;
}

__global__ void k_mlp0(const float* __restrict__ y0, const float* __restrict__ W1,
                       const float* __restrict__ b1, const float* __restrict__ g,
                       const float* __restrict__ be, const float* __restrict__ m,
                       const float* __restrict__ v, float* __restrict__ out){
    int idx = blockIdx.x*256 + threadIdx.x;
    if (idx >= NN*HH) return;
    int i = idx >> 7, j = idx & 127;
    float acc = b1[j] + y0[3*i]*W1[j] + y0[3*i+1]*W1[HH+j] + y0[3*i+2]*W1[2*HH+j];
    float r = rsqrtf(v[j] + 1e-5f);
    acc = g[j]*(acc - m[j])*r + be[j];
    out[idx] = fmaxf(acc, 0.f);
}

// ---------------- fused [agg?]+GEMM: out = relu(BN(agg(A) @ W + b)) ------------
// 256 threads, 64-row tile, 4 waves x one 16-row MFMA tile.
// Phase 1: 8 half-waves gather/stream rows (coalesced 512B row loads),
//   trunc-split to bf16 hi/lo, store LDS in fragment order.
//   Element (r,c): tile=r>>4, m=r&15, kc=c>>5, q=(c>>3)&3, j=c&7.
//   chunk' = (m*4+q) ^ (kc*2); pos = ((tile*4+kc)*64 + chunk')*8 + j.
//   Write banks: 4*(chunk'&7)+j1/2 spans 16 banks over a half-wave -> ~free.
// Phase 2: lane l reads chunk' = ((l&15)*4 + (l>>4)) ^ (kc*2): bijective ->
//   conflict-free ds b128; bf16x3 MFMA vs L2-resident pre-swizzled Wp.
__global__ __launch_bounds__(256)
void k_gemm2(const float* __restrict__ A, const int* __restrict__ rp,
             const int* __restrict__ ssrc, const short* __restrict__ Wp,
             const float* __restrict__ bias, const float* __restrict__ g,
             const float* __restrict__ be, const float* __restrict__ m,
             const float* __restrict__ v, int use_bn,
             float* __restrict__ out){
    __shared__ short sAh[8192];
    __shared__ short sAl[8192];
    const int t = threadIdx.x;
    const int R0 = blockIdx.x * 64;

    // ---- phase 1 ----
    {
        int hw = t >> 5, ln = t & 31;
        int c4 = ln << 2;
        int kc1 = c4 >> 5, q1 = (c4 >> 3) & 3, j1 = c4 & 7;
        const float* Ac = A + c4;
        for (int r = hw; r < 64; r += 8){
            int node = R0 + r;
            float4 a0 = *(const float4*)&Ac[(size_t)node*HH];
            if (rp && node < NN){
                int b = rp[node], e = rp[node+1];
                float4 a1 = {0,0,0,0}, a2 = {0,0,0,0}, a3 = {0,0,0,0};
                int k = b;
                for (; k + 3 < e; k += 4){
                    int s0 = ssrc[k], s1 = ssrc[k+1], s2 = ssrc[k+2], s3 = ssrc[k+3];
                    float4 t0 = *(const float4*)&Ac[(size_t)s0*HH];
                    float4 t1 = *(const float4*)&Ac[(size_t)s1*HH];
                    float4 t2 = *(const float4*)&Ac[(size_t)s2*HH];
                    float4 t3 = *(const float4*)&Ac[(size_t)s3*HH];
                    a0.x+=t0.x; a0.y+=t0.y; a0.z+=t0.z; a0.w+=t0.w;
                    a1.x+=t1.x; a1.y+=t1.y; a1.z+=t1.z; a1.w+=t1.w;
                    a2.x+=t2.x; a2.y+=t2.y; a2.z+=t2.z; a2.w+=t2.w;
                    a3.x+=t3.x; a3.y+=t3.y; a3.z+=t3.z; a3.w+=t3.w;
                }
                if (k + 1 < e){
                    int s0 = ssrc[k], s1 = ssrc[k+1];
                    float4 t0 = *(const float4*)&Ac[(size_t)s0*HH];
                    float4 t1 = *(const float4*)&Ac[(size_t)s1*HH];
                    a0.x+=t0.x; a0.y+=t0.y; a0.z+=t0.z; a0.w+=t0.w;
                    a1.x+=t1.x; a1.y+=t1.y; a1.z+=t1.z; a1.w+=t1.w;
                    k += 2;
                }
                if (k < e){
                    int s0 = ssrc[k];
                    float4 t0 = *(const float4*)&Ac[(size_t)s0*HH];
                    a0.x+=t0.x; a0.y+=t0.y; a0.z+=t0.z; a0.w+=t0.w;
                }
                a0.x += a1.x+a2.x+a3.x; a0.y += a1.y+a2.y+a3.y;
                a0.z += a1.z+a2.z+a3.z; a0.w += a1.w+a2.w+a3.w;
            }
            int tile = r >> 4, mm = r & 15;
            int chunk = ((mm << 2) + q1) ^ (kc1 << 1);
            int pos = (((tile << 2) + kc1)*64 + chunk)*8 + j1;
            float xs[4] = {a0.x, a0.y, a0.z, a0.w};
            unsigned hp[2], lp[2];
#pragma unroll
            for (int i = 0; i < 2; i++){
                unsigned u0 = __float_as_uint(xs[2*i]);
                unsigned u1 = __float_as_uint(xs[2*i+1]);
                float r0 = xs[2*i]   - __uint_as_float(u0 & 0xFFFF0000u);
                float r1 = xs[2*i+1] - __uint_as_float(u1 & 0xFFFF0000u);
                hp[i] = (u0 >> 16) | (u1 & 0xFFFF0000u);
                lp[i] = (__float_as_uint(r0) >> 16) | (__float_as_uint(r1) & 0xFFFF0000u);
            }
            *(uint2*)&sAh[pos] = make_uint2(hp[0], hp[1]);
            *(uint2*)&sAl[pos] = make_uint2(lp[0], lp[1]);
        }
    }
    __syncthreads();

    // ---- phase 2: wave w computes rows [R0+w*16, R0+w*16+16) x 128 cols ----
    const int w = t >> 6, l = t & 63;
    const int n = l & 15, q = l >> 4;
    const short* Wh = Wp;
    const short* Wl = Wp + 16384;

    f32x4 acc[8];
#pragma unroll
    for (int ct = 0; ct < 8; ct++) acc[ct] = (f32x4){0.f,0.f,0.f,0.f};

#pragma unroll
    for (int kc = 0; kc < 4; kc++){
        int chunk = ((n << 2) + q) ^ (kc << 1);
        int p0 = (((w << 2) + kc)*64 + chunk)*8;
        bf16x8 ah = *(const bf16x8*)&sAh[p0];
        bf16x8 al = *(const bf16x8*)&sAl[p0];
        const short* ph = Wh + (size_t)(kc*8)*512 + l*8;
        const short* pl = Wl + (size_t)(kc*8)*512 + l*8;
#pragma unroll
        for (int ct = 0; ct < 8; ct++){
            bf16x8 bh = *(const bf16x8*)(ph + ct*512);
            bf16x8 bl = *(const bf16x8*)(pl + ct*512);
            acc[ct] = __builtin_amdgcn_mfma_f32_16x16x32_bf16(ah, bh, acc[ct], 0, 0, 0);
            acc[ct] = __builtin_amdgcn_mfma_f32_16x16x32_bf16(al, bh, acc[ct], 0, 0, 0);
            acc[ct] = __builtin_amdgcn_mfma_f32_16x16x32_bf16(ah, bl, acc[ct], 0, 0, 0);
        }
    }

    // ---- epilogue: out = relu(sc*acc + sh) ----
#pragma unroll
    for (int ct = 0; ct < 8; ct++){
        int j = (ct << 4) + n;
        float scv, shv;
        if (use_bn){
            float rr = rsqrtf(v[j] + 1e-5f);
            float gg = g[j]*rr;
            scv = gg;
            shv = be[j] + gg*(bias[j] - m[j]);
        } else {
            scv = 1.f;
            shv = bias[j];
        }
#pragma unroll
        for (int r = 0; r < 4; r++){
            int row = R0 + w*16 + q*4 + r;
            out[(size_t)row*HH + j] = fmaxf(fmaf(acc[ct][r], scv, shv), 0.f);
        }
    }
}

// ---------------- pooling + classifier: block per graph, no atomics ---------
__global__ void k_pool2(const float* __restrict__ h, const float* __restrict__ Wc,
                        const float* __restrict__ bc, const int* __restrict__ rp_g,
                        float* __restrict__ out){
    __shared__ float ws[4];
    int g = blockIdx.x, t = threadIdx.x;
    long beg = (long)rp_g[g]*HH, end = (long)rp_g[g+1]*HH;
    float s = 0.f;
    for (long i = beg + t; i < end; i += 256) s += h[i]*Wc[(int)(i & 127)];
    int lane = t & 63, w = t >> 6;
#pragma unroll
    for (int off = 32; off > 0; off >>= 1) s += __shfl_down(s, off);
    if (lane == 0) ws[w] = s;
    __syncthreads();
    if (t == 0) out[g] = bc[0] + ws[0] + ws[1] + ws[2] + ws[3];
}

extern "C" void kernel_launch(void* const* d_in, const int* in_sizes, int n_in,
                              void* d_out, int out_size, void* d_ws, size_t ws_size,
                              hipStream_t stream){
    const float* x     = (const float*)d_in[0];
    const int*   ei    = (const int*)d_in[1];
    const int*   batch = (const int*)d_in[2];
    const float* W1_0  = (const float*)d_in[3];
    const float* b1_0  = (const float*)d_in[4];
    const float* g_0   = (const float*)d_in[5];
    const float* be_0  = (const float*)d_in[6];
    const float* m_0   = (const float*)d_in[7];
    const float* v_0   = (const float*)d_in[8];
    const float* W2_0  = (const float*)d_in[9];
    const float* b2_0  = (const float*)d_in[10];
    const float* W1s   = (const float*)d_in[11];
    const float* b1s   = (const float*)d_in[12];
    const float* gs    = (const float*)d_in[13];
    const float* bes   = (const float*)d_in[14];
    const float* ms    = (const float*)d_in[15];
    const float* vs    = (const float*)d_in[16];
    const float* W2s   = (const float*)d_in[17];
    const float* b2s   = (const float*)d_in[18];
    const float* Wc    = (const float*)d_in[19];
    const float* bc    = (const float*)d_in[20];

    float* P0 = (float*)d_ws;
    float* P1 = P0 + (size_t)NPAD*HH;
    int* rp    = (int*)(P1 + (size_t)NPAD*HH);
    int* fill  = rp + (NN + 1);
    int* ssrc  = fill + NN;
    int* bsums = ssrc + EE;
    int* rp_g  = bsums + 128;
    size_t wp_off = (size_t)(rp_g + (GG + 1) - (int*)d_ws);
    wp_off = (wp_off + 3) & ~(size_t)3;
    short* Wp = (short*)((int*)d_ws + wp_off);

    const int* src = ei;
    const int* dst = ei + EE;

    // --- CSR build ---
    k_zero_i32<<<(NN+255)/256, 256, 0, stream>>>(fill, NN);
    k_hist<<<(EE+255)/256, 256, 0, stream>>>(dst, fill);
    k_scan1<<<98, 256, 0, stream>>>(fill, rp, bsums, NN);
    k_scan2<<<1, 128, 0, stream>>>(bsums, 98);
    k_scan3<<<(NN+255)/256, 256, 0, stream>>>(rp, bsums, fill, NN);
    k_place<<<(EE+255)/256, 256, 0, stream>>>(src, dst, fill, ssrc);

    // --- graph rowptr + weight pre-swizzle ---
    k_bounds<<<(NN+255)/256, 256, 0, stream>>>(batch, rp_g);
    k_wprep<<<(9*16384)/256, 256, 0, stream>>>(W2_0, W1s, W2s, Wp);

    // --- layer 0 (in=3) ---
    k_agg3<<<(NN+255)/256, 256, 0, stream>>>(x, rp, ssrc, P0);
    k_mlp0<<<(NN*HH)/256, 256, 0, stream>>>(P0, W1_0, b1_0, g_0, be_0, m_0, v_0, P1);
    k_gemm2<<<NBLK2, 256, 0, stream>>>(P1, nullptr, nullptr, Wp, b2_0,
                                       nullptr, nullptr, nullptr, nullptr, 0, P0);

    // --- layers 1..4: fused(agg+GEMM1) then plain GEMM2 ---
    for (int l = 0; l < 4; l++){
        k_gemm2<<<NBLK2, 256, 0, stream>>>(P0, rp, ssrc, Wp + (size_t)(1+l)*32768,
                                           b1s + l*HH, gs + l*HH, bes + l*HH,
                                           ms + l*HH, vs + l*HH, 1, P1);
        k_gemm2<<<NBLK2, 256, 0, stream>>>(P1, nullptr, nullptr, Wp + (size_t)(5+l)*32768,
                                           b2s + l*HH, nullptr, nullptr, nullptr, nullptr,
                                           0, P0);
    }

    // --- pooling + classifier (no atomics) ---
    k_pool2<<<GG, 256, 0, stream>>>(P0, Wc, bc, rp_g, (float*)d_out);
}

// Round 7
// 646.916 us; speedup vs baseline: 1.3525x; 1.0970x over previous
//
#include <hip/hip_runtime.h>

#define NN 100000
#define EE 600000
#define HH 128
#define GG 1000
#define NPAD 100096   // 1564 * 64
#define NBLK2 1564

typedef __attribute__((ext_vector_type(8))) short bf16x8;
typedef __attribute__((ext_vector_type(4))) float f32x4;

__device__ inline short f2bf(float x){
    unsigned u = __float_as_uint(x);
    unsigned r = (u + 0x7FFFu + ((u >> 16) & 1u)) >> 16;
    return (short)r;
}
__device__ inline float bf2f(short h){
    unsigned u = ((unsigned)(unsigned short)h) << 16;
    return __uint_as_float(u);
}

// ---------------- CSR build ----------------
__global__ void k_zero_i32(int* __restrict__ p, int n){
    int i = blockIdx.x*256 + threadIdx.x;
    if (i < n) p[i] = 0;
}

__global__ void k_hist(const int* __restrict__ dst, int* __restrict__ cnt){
    int e = blockIdx.x*256 + threadIdx.x;
    if (e < EE) atomicAdd(&cnt[dst[e]], 1);
}

__global__ void k_scan1(const int* __restrict__ cnt, int* __restrict__ excl,
                        int* __restrict__ bsums, int n){
    __shared__ int wsum[4];
    int t = threadIdx.x;
    int idx = blockIdx.x*1024 + t*4;
    int c[4];
#pragma unroll
    for (int i = 0; i < 4; i++) c[i] = (idx+i < n) ? cnt[idx+i] : 0;
    int s = c[0]+c[1]+c[2]+c[3];
    int lane = t & 63, w = t >> 6;
    int x = s;
#pragma unroll
    for (int off = 1; off < 64; off <<= 1){
        int y = __shfl_up(x, off);
        if (lane >= off) x += y;
    }
    if (lane == 63) wsum[w] = x;
    __syncthreads();
    int woff = 0;
    for (int i = 0; i < w; i++) woff += wsum[i];
    int run = woff + x - s;
#pragma unroll
    for (int i = 0; i < 4; i++){
        if (idx+i < n) excl[idx+i] = run;
        run += c[i];
    }
    if (t == 255) bsums[blockIdx.x] = woff + x;
}

__global__ void k_scan2(int* __restrict__ bsums, int nb){
    __shared__ int ws2[2];
    int t = threadIdx.x;
    int v = (t < nb) ? bsums[t] : 0;
    int lane = t & 63, w = t >> 6;
    int x = v;
#pragma unroll
    for (int off = 1; off < 64; off <<= 1){
        int y = __shfl_up(x, off);
        if (lane >= off) x += y;
    }
    if (lane == 63) ws2[w] = x;
    __syncthreads();
    int off0 = (w == 1) ? ws2[0] : 0;
    if (t < nb) bsums[t] = off0 + x - v;
}

__global__ void k_scan3(int* __restrict__ rp, const int* __restrict__ bsums,
                        int* __restrict__ fill, int n){
    int i = blockIdx.x*256 + threadIdx.x;
    if (i < n){
        int r = rp[i] + bsums[i >> 10];
        rp[i] = r;
        fill[i] = r;
    }
    if (i == 0) rp[n] = EE;
}

__global__ void k_place(const int* __restrict__ src, const int* __restrict__ dst,
                        int* __restrict__ fill, int* __restrict__ ssrc){
    int e = blockIdx.x*256 + threadIdx.x;
    if (e < EE){
        int p = atomicAdd(&fill[dst[e]], 1);
        ssrc[p] = src[e];
    }
}

// ---------------- graph rowptr from sorted batch ----------------
__global__ void k_bounds(const int* __restrict__ batch, int* __restrict__ rp_g){
    int i = blockIdx.x*256 + threadIdx.x;
    if (i >= NN) return;
    int b = batch[i];
    if (i == 0){
        for (int g = 0; g <= b; g++) rp_g[g] = 0;
    } else {
        int p = batch[i-1];
        for (int g = p+1; g <= b; g++) rp_g[g] = i;
    }
    if (i == NN-1){
        for (int g = b+1; g <= GG; g++) rp_g[g] = NN;
    }
}

// ---------------- W pre-swizzle into bf16 hi/lo B-fragment order ----------
// frag(kc, ct, l) at ((kc*8 + ct)*64 + l)*8 + j ; value W[kc*32+(l>>4)*8+j][ct*16+(l&15)]
__global__ void k_wprep(const float* __restrict__ W2_0, const float* __restrict__ W1s,
                        const float* __restrict__ W2s, short* __restrict__ Wp){
    int tid = blockIdx.x*256 + threadIdx.x;
    if (tid >= 9*16384) return;
    int m = tid >> 14;
    int r = tid & 16383;
    int j = r & 7, l = (r >> 3) & 63, ctkc = r >> 9;
    int ct = ctkc & 7, kc = ctkc >> 3;
    int k = kc*32 + ((l >> 4) << 3) + j;
    int n = (ct << 4) + (l & 15);
    const float* W = (m == 0) ? W2_0
                   : (m <= 4) ? (W1s + (size_t)(m-1)*HH*HH)
                              : (W2s + (size_t)(m-5)*HH*HH);
    float w = W[k*HH + n];
    short hi = f2bf(w);
    short lo = f2bf(w - bf2f(hi));
    short* base = Wp + (size_t)m*32768;
    base[r] = hi;
    base[16384 + r] = lo;
}

// ---------------- layer 0 aggregation (in=3) ----------------
__global__ void k_agg3(const float* __restrict__ x, const int* __restrict__ rp,
                       const int* __restrict__ ssrc, float* __restrict__ y){
    int i = blockIdx.x*256 + threadIdx.x;
    if (i >= NN) return;
    float a0 = x[3*i], a1 = x[3*i+1], a2 = x[3*i+2];
    int b = rp[i], e = rp[i+1];
    for (int k = b; k < e; k++){
        int s = ssrc[k];
        a0 += x[3*s]; a1 += x[3*s+1]; a2 += x[3*s+2];
    }
    y[3*i] = a0; y[3*i+1] = a1; y[3*i+2] = a2;
}

// ================== shared MFMA helpers ==================
// phase-1/2 LDS layout (bf16 hi/lo planes):
//   element (r,c): tile=r>>4, m=r&15, kc=c>>5, q=(c>>3)&3, j=c&7
//   chunk = ((m<<2)|q) ^ (kc<<1); pos = ((tile*4+kc)*64 + chunk)*8 + j
// phase-3/4 LDS layout (fp32 plane, same 32KB union):
//   chunk = ((m<<2)|q2) ^ (kc<<1) ^ (m>>2); pos = ((tile*4+kc)*64+chunk)*8 + j

__device__ inline void mfma_gemm_128(const short* __restrict__ sAh,
                                     const short* __restrict__ sAl,
                                     const short* __restrict__ Wp,
                                     int w, int l, f32x4* acc){
    const short* Wh = Wp;
    const short* Wl = Wp + 16384;
    const int n = l & 15, q = l >> 4;
#pragma unroll
    for (int ct = 0; ct < 8; ct++) acc[ct] = (f32x4){0.f,0.f,0.f,0.f};
#pragma unroll
    for (int kc = 0; kc < 4; kc++){
        int chunk = ((n << 2) + q) ^ (kc << 1);
        int p0 = (((w << 2) + kc)*64 + chunk)*8;
        bf16x8 ah = *(const bf16x8*)&sAh[p0];
        bf16x8 al = *(const bf16x8*)&sAl[p0];
        const short* ph = Wh + (size_t)(kc*8)*512 + l*8;
        const short* pl = Wl + (size_t)(kc*8)*512 + l*8;
#pragma unroll
        for (int ct = 0; ct < 8; ct++){
            bf16x8 bh = *(const bf16x8*)(ph + ct*512);
            bf16x8 bl = *(const bf16x8*)(pl + ct*512);
            acc[ct] = __builtin_amdgcn_mfma_f32_16x16x32_bf16(ah, bh, acc[ct], 0, 0, 0);
            acc[ct] = __builtin_amdgcn_mfma_f32_16x16x32_bf16(al, bh, acc[ct], 0, 0, 0);
            acc[ct] = __builtin_amdgcn_mfma_f32_16x16x32_bf16(ah, bl, acc[ct], 0, 0, 0);
        }
    }
}

// ---------------- layer 0 fused: mlp0(phase1) + GEMM(W2_0) ----------------
__global__ __launch_bounds__(256)
void k_layer0(const float* __restrict__ y0, const short* __restrict__ Wp,
              const float* __restrict__ W1, const float* __restrict__ b1,
              const float* __restrict__ g, const float* __restrict__ be,
              const float* __restrict__ m, const float* __restrict__ v,
              const float* __restrict__ b2, float* __restrict__ out){
    __shared__ __align__(16) char smem[32768];
    short* sAh = (short*)smem;
    short* sAl = (short*)(smem + 16384);
    const int t = threadIdx.x;
    const int R0 = blockIdx.x * 64;

    // phase 1: h1 = relu(BN(y0 @ W1 + b1)) for 4 cols, split -> LDS
    {
        int hw = t >> 5, ln = t & 31;
        int c4 = ln << 2;
        int kc1 = c4 >> 5, q1 = (c4 >> 3) & 3, j1 = c4 & 7;
        float Wc[3][4], Ac[4], Bc[4];
#pragma unroll
        for (int i = 0; i < 4; i++){
            int c = c4 + i;
            float rs = rsqrtf(v[c] + 1e-5f);
            float sc = g[c]*rs;
            Ac[i] = sc;
            Bc[i] = sc*(b1[c] - m[c]) + be[c];
            Wc[0][i] = W1[c]; Wc[1][i] = W1[HH + c]; Wc[2][i] = W1[2*HH + c];
        }
        for (int r = hw; r < 64; r += 8){
            int node = R0 + r;
            float y0a = y0[3*node], y0b = y0[3*node+1], y0c = y0[3*node+2];
            float xs[4];
#pragma unroll
            for (int i = 0; i < 4; i++){
                float raw = y0a*Wc[0][i] + y0b*Wc[1][i] + y0c*Wc[2][i];
                xs[i] = fmaxf(fmaf(raw, Ac[i], Bc[i]), 0.f);
            }
            int tile = r >> 4, mm = r & 15;
            int chunk = ((mm << 2) + q1) ^ (kc1 << 1);
            int pos = (((tile << 2) + kc1)*64 + chunk)*8 + j1;
            unsigned hp[2], lp[2];
#pragma unroll
            for (int i = 0; i < 2; i++){
                unsigned u0 = __float_as_uint(xs[2*i]);
                unsigned u1 = __float_as_uint(xs[2*i+1]);
                float r0 = xs[2*i]   - __uint_as_float(u0 & 0xFFFF0000u);
                float r1 = xs[2*i+1] - __uint_as_float(u1 & 0xFFFF0000u);
                hp[i] = (u0 >> 16) | (u1 & 0xFFFF0000u);
                lp[i] = (__float_as_uint(r0) >> 16) | (__float_as_uint(r1) & 0xFFFF0000u);
            }
            *(uint2*)&sAh[pos] = make_uint2(hp[0], hp[1]);
            *(uint2*)&sAl[pos] = make_uint2(lp[0], lp[1]);
        }
    }
    __syncthreads();

    // phase 2: GEMM vs W2_0, bias+relu epilogue
    const int w = t >> 6, l = t & 63;
    const int n = l & 15, q = l >> 4;
    f32x4 acc[8];
    mfma_gemm_128(sAh, sAl, Wp, w, l, acc);
#pragma unroll
    for (int ct = 0; ct < 8; ct++){
        int j = (ct << 4) + n;
        float shv = b2[j];
#pragma unroll
        for (int r = 0; r < 4; r++){
            int row = R0 + w*16 + q*4 + r;
            out[(size_t)row*HH + j] = fmaxf(acc[ct][r] + shv, 0.f);
        }
    }
}

// ---------------- full GIN layer fused: agg + GEMM1+BN+ReLU + GEMM2+b+ReLU ----
__global__ __launch_bounds__(256)
void k_layer(const float* __restrict__ A, const int* __restrict__ rp,
             const int* __restrict__ ssrc,
             const short* __restrict__ Wp1, const short* __restrict__ Wp2,
             const float* __restrict__ b1, const float* __restrict__ g,
             const float* __restrict__ be, const float* __restrict__ m,
             const float* __restrict__ v, const float* __restrict__ b2,
             float* __restrict__ out){
    __shared__ __align__(16) char smem[32768];
    short* sAh = (short*)smem;
    short* sAl = (short*)(smem + 16384);
    float* sF  = (float*)smem;
    const int t = threadIdx.x;
    const int R0 = blockIdx.x * 64;

    // ---- phase 1: gather+sum rows, split, -> LDS ----
    {
        int hw = t >> 5, ln = t & 31;
        int c4 = ln << 2;
        int kc1 = c4 >> 5, q1 = (c4 >> 3) & 3, j1 = c4 & 7;
        const float* Ac = A + c4;
        for (int r = hw; r < 64; r += 8){
            int node = R0 + r;
            float4 a0 = *(const float4*)&Ac[(size_t)node*HH];
            if (node < NN){
                int b = rp[node], e = rp[node+1];
                float4 a1 = {0,0,0,0}, a2 = {0,0,0,0}, a3 = {0,0,0,0};
                int k = b;
                for (; k + 3 < e; k += 4){
                    int s0 = ssrc[k], s1 = ssrc[k+1], s2 = ssrc[k+2], s3 = ssrc[k+3];
                    float4 t0 = *(const float4*)&Ac[(size_t)s0*HH];
                    float4 t1 = *(const float4*)&Ac[(size_t)s1*HH];
                    float4 t2 = *(const float4*)&Ac[(size_t)s2*HH];
                    float4 t3 = *(const float4*)&Ac[(size_t)s3*HH];
                    a0.x+=t0.x; a0.y+=t0.y; a0.z+=t0.z; a0.w+=t0.w;
                    a1.x+=t1.x; a1.y+=t1.y; a1.z+=t1.z; a1.w+=t1.w;
                    a2.x+=t2.x; a2.y+=t2.y; a2.z+=t2.z; a2.w+=t2.w;
                    a3.x+=t3.x; a3.y+=t3.y; a3.z+=t3.z; a3.w+=t3.w;
                }
                if (k + 1 < e){
                    int s0 = ssrc[k], s1 = ssrc[k+1];
                    float4 t0 = *(const float4*)&Ac[(size_t)s0*HH];
                    float4 t1 = *(const float4*)&Ac[(size_t)s1*HH];
                    a0.x+=t0.x; a0.y+=t0.y; a0.z+=t0.z; a0.w+=t0.w;
                    a1.x+=t1.x; a1.y+=t1.y; a1.z+=t1.z; a1.w+=t1.w;
                    k += 2;
                }
                if (k < e){
                    int s0 = ssrc[k];
                    float4 t0 = *(const float4*)&Ac[(size_t)s0*HH];
                    a0.x+=t0.x; a0.y+=t0.y; a0.z+=t0.z; a0.w+=t0.w;
                }
                a0.x += a1.x+a2.x+a3.x; a0.y += a1.y+a2.y+a3.y;
                a0.z += a1.z+a2.z+a3.z; a0.w += a1.w+a2.w+a3.w;
            }
            int tile = r >> 4, mm = r & 15;
            int chunk = ((mm << 2) + q1) ^ (kc1 << 1);
            int pos = (((tile << 2) + kc1)*64 + chunk)*8 + j1;
            float xs[4] = {a0.x, a0.y, a0.z, a0.w};
            unsigned hp[2], lp[2];
#pragma unroll
            for (int i = 0; i < 2; i++){
                unsigned u0 = __float_as_uint(xs[2*i]);
                unsigned u1 = __float_as_uint(xs[2*i+1]);
                float r0 = xs[2*i]   - __uint_as_float(u0 & 0xFFFF0000u);
                float r1 = xs[2*i+1] - __uint_as_float(u1 & 0xFFFF0000u);
                hp[i] = (u0 >> 16) | (u1 & 0xFFFF0000u);
                lp[i] = (__float_as_uint(r0) >> 16) | (__float_as_uint(r1) & 0xFFFF0000u);
            }
            *(uint2*)&sAh[pos] = make_uint2(hp[0], hp[1]);
            *(uint2*)&sAl[pos] = make_uint2(lp[0], lp[1]);
        }
    }
    __syncthreads();

    const int w = t >> 6, l = t & 63;
    const int n = l & 15, q = l >> 4;

    // ---- phase 2: GEMM1 + BN/ReLU in regs ----
    f32x4 acc[8];
    mfma_gemm_128(sAh, sAl, Wp1, w, l, acc);
    float val[8][4];
#pragma unroll
    for (int ct = 0; ct < 8; ct++){
        int j = (ct << 4) + n;
        float rr = rsqrtf(v[j] + 1e-5f);
        float scv = g[j]*rr;
        float shv = be[j] + scv*(b1[j] - m[j]);
#pragma unroll
        for (int r = 0; r < 4; r++)
            val[ct][r] = fmaxf(fmaf(acc[ct][r], scv, shv), 0.f);
    }
    __syncthreads();   // all phase-2 LDS reads done before overwrite

    // ---- phase 3: write fp32 intermediate into LDS (fragment order) ----
    // lane holds (row m2=q*4+r in tile w, col = ct*16+n)
#pragma unroll
    for (int ct = 0; ct < 8; ct++){
        int kc = ct >> 1;
        int q2 = ((ct & 1) << 1) | (n >> 3);
        int j = n & 7;
#pragma unroll
        for (int r = 0; r < 4; r++){
            int m2 = q*4 + r;
            int chunk = (((m2 << 2) | q2) ^ (kc << 1)) ^ q;
            sF[(((w << 2) + kc)*64 + chunk)*8 + j] = val[ct][r];
        }
    }
    __syncthreads();

    // ---- phase 4: read frags, split, GEMM2 + bias/ReLU -> global ----
    {
        const short* Wh = Wp2;
        const short* Wl = Wp2 + 16384;
        f32x4 acc2[8];
#pragma unroll
        for (int ct = 0; ct < 8; ct++) acc2[ct] = (f32x4){0.f,0.f,0.f,0.f};
#pragma unroll
        for (int kc = 0; kc < 4; kc++){
            int chunk = (((n << 2) | q) ^ (kc << 1)) ^ (n >> 2);
            int base = (((w << 2) + kc)*64 + chunk)*8;
            float4 fa = *(const float4*)&sF[base];
            float4 fb = *(const float4*)&sF[base + 4];
            float xs[8] = {fa.x,fa.y,fa.z,fa.w,fb.x,fb.y,fb.z,fb.w};
            bf16x8 ah, al;
#pragma unroll
            for (int i = 0; i < 8; i++){
                unsigned u = __float_as_uint(xs[i]);
                ah[i] = (short)(u >> 16);
                float rv = xs[i] - __uint_as_float(u & 0xFFFF0000u);
                al[i] = (short)(__float_as_uint(rv) >> 16);
            }
            const short* ph = Wh + (size_t)(kc*8)*512 + l*8;
            const short* pl = Wl + (size_t)(kc*8)*512 + l*8;
#pragma unroll
            for (int ct = 0; ct < 8; ct++){
                bf16x8 bh = *(const bf16x8*)(ph + ct*512);
                bf16x8 bl = *(const bf16x8*)(pl + ct*512);
                acc2[ct] = __builtin_amdgcn_mfma_f32_16x16x32_bf16(ah, bh, acc2[ct], 0, 0, 0);
                acc2[ct] = __builtin_amdgcn_mfma_f32_16x16x32_bf16(al, bh, acc2[ct], 0, 0, 0);
                acc2[ct] = __builtin_amdgcn_mfma_f32_16x16x32_bf16(ah, bl, acc2[ct], 0, 0, 0);
            }
        }
#pragma unroll
        for (int ct = 0; ct < 8; ct++){
            int j = (ct << 4) + n;
            float shv = b2[j];
#pragma unroll
            for (int r = 0; r < 4; r++){
                int row = R0 + w*16 + q*4 + r;
                out[(size_t)row*HH + j] = fmaxf(acc2[ct][r] + shv, 0.f);
            }
        }
    }
}

// ---------------- pooling + classifier: block per graph, no atomics ---------
__global__ void k_pool2(const float* __restrict__ h, const float* __restrict__ Wc,
                        const float* __restrict__ bc, const int* __restrict__ rp_g,
                        float* __restrict__ out){
    __shared__ float ws[4];
    int g = blockIdx.x, t = threadIdx.x;
    long beg = (long)rp_g[g]*HH, end = (long)rp_g[g+1]*HH;
    float s = 0.f;
    for (long i = beg + t; i < end; i += 256) s += h[i]*Wc[(int)(i & 127)];
    int lane = t & 63, w = t >> 6;
#pragma unroll
    for (int off = 32; off > 0; off >>= 1) s += __shfl_down(s, off);
    if (lane == 0) ws[w] = s;
    __syncthreads();
    if (t == 0) out[g] = bc[0] + ws[0] + ws[1] + ws[2] + ws[3];
}

extern "C" void kernel_launch(void* const* d_in, const int* in_sizes, int n_in,
                              void* d_out, int out_size, void* d_ws, size_t ws_size,
                              hipStream_t stream){
    const float* x     = (const float*)d_in[0];
    const int*   ei    = (const int*)d_in[1];
    const int*   batch = (const int*)d_in[2];
    const float* W1_0  = (const float*)d_in[3];
    const float* b1_0  = (const float*)d_in[4];
    const float* g_0   = (const float*)d_in[5];
    const float* be_0  = (const float*)d_in[6];
    const float* m_0   = (const float*)d_in[7];
    const float* v_0   = (const float*)d_in[8];
    const float* W2_0  = (const float*)d_in[9];
    const float* b2_0  = (const float*)d_in[10];
    const float* W1s   = (const float*)d_in[11];
    const float* b1s   = (const float*)d_in[12];
    const float* gs    = (const float*)d_in[13];
    const float* bes   = (const float*)d_in[14];
    const float* ms    = (const float*)d_in[15];
    const float* vs    = (const float*)d_in[16];
    const float* W2s   = (const float*)d_in[17];
    const float* b2s   = (const float*)d_in[18];
    const float* Wc    = (const float*)d_in[19];
    const float* bc    = (const float*)d_in[20];

    float* P0 = (float*)d_ws;
    float* P1 = P0 + (size_t)NPAD*HH;
    int* rp    = (int*)(P1 + (size_t)NPAD*HH);
    int* fill  = rp + (NN + 1);
    int* ssrc  = fill + NN;
    int* bsums = ssrc + EE;
    int* rp_g  = bsums + 128;
    size_t wp_off = (size_t)(rp_g + (GG + 1) - (int*)d_ws);
    wp_off = (wp_off + 3) & ~(size_t)3;
    short* Wp = (short*)((int*)d_ws + wp_off);

    const int* src = ei;
    const int* dst = ei + EE;

    // --- CSR build ---
    k_zero_i32<<<(NN+255)/256, 256, 0, stream>>>(fill, NN);
    k_hist<<<(EE+255)/256, 256, 0, stream>>>(dst, fill);
    k_scan1<<<98, 256, 0, stream>>>(fill, rp, bsums, NN);
    k_scan2<<<1, 128, 0, stream>>>(bsums, 98);
    k_scan3<<<(NN+255)/256, 256, 0, stream>>>(rp, bsums, fill, NN);
    k_place<<<(EE+255)/256, 256, 0, stream>>>(src, dst, fill, ssrc);

    // --- graph rowptr + weight pre-swizzle ---
    k_bounds<<<(NN+255)/256, 256, 0, stream>>>(batch, rp_g);
    k_wprep<<<(9*16384)/256, 256, 0, stream>>>(W2_0, W1s, W2s, Wp);

    // --- layer 0: agg3 -> fused mlp0+GEMM(W2_0) ---
    k_agg3<<<(NN+255)/256, 256, 0, stream>>>(x, rp, ssrc, P1);
    k_layer0<<<NBLK2, 256, 0, stream>>>(P1, Wp, W1_0, b1_0, g_0, be_0, m_0, v_0,
                                        b2_0, P0);

    // --- layers 1..4: one fused kernel per layer ---
    float* cur = P0; float* oth = P1;
    for (int l = 0; l < 4; l++){
        k_layer<<<NBLK2, 256, 0, stream>>>(cur, rp, ssrc,
                                           Wp + (size_t)(1+l)*32768,
                                           Wp + (size_t)(5+l)*32768,
                                           b1s + l*HH, gs + l*HH, bes + l*HH,
                                           ms + l*HH, vs + l*HH, b2s + l*HH,
                                           oth);
        float* tmp = cur; cur = oth; oth = tmp;
    }

    // --- pooling + classifier (no atomics) ---
    k_pool2<<<GG, 256, 0, stream>>>(cur, Wc, bc, rp_g, (float*)d_out);
}

// Round 8
// 631.047 us; speedup vs baseline: 1.3865x; 1.0251x over previous
//
#include <hip/hip_runtime.h>

#define NN 100000
#define EE 600000
#define HH 128
#define GG 1000
#define NPAD 100096   // 1564 * 64
#define NBLK2 1564

typedef __attribute__((ext_vector_type(8))) short bf16x8;
typedef __attribute__((ext_vector_type(4))) float f32x4;

__device__ inline short f2bf(float x){
    unsigned u = __float_as_uint(x);
    unsigned r = (u + 0x7FFFu + ((u >> 16) & 1u)) >> 16;
    return (short)r;
}
__device__ inline float bf2f(short h){
    unsigned u = ((unsigned)(unsigned short)h) << 16;
    return __uint_as_float(u);
}

// ---------------- CSR build ----------------
__global__ void k_zero_i32(int* __restrict__ p, int n){
    int i = blockIdx.x*256 + threadIdx.x;
    if (i < n) p[i] = 0;
}

__global__ void k_hist(const int* __restrict__ dst, int* __restrict__ cnt){
    int e = blockIdx.x*256 + threadIdx.x;
    if (e < EE) atomicAdd(&cnt[dst[e]], 1);
}

__global__ void k_scan1(const int* __restrict__ cnt, int* __restrict__ excl,
                        int* __restrict__ bsums, int n){
    __shared__ int wsum[4];
    int t = threadIdx.x;
    int idx = blockIdx.x*1024 + t*4;
    int c[4];
#pragma unroll
    for (int i = 0; i < 4; i++) c[i] = (idx+i < n) ? cnt[idx+i] : 0;
    int s = c[0]+c[1]+c[2]+c[3];
    int lane = t & 63, w = t >> 6;
    int x = s;
#pragma unroll
    for (int off = 1; off < 64; off <<= 1){
        int y = __shfl_up(x, off);
        if (lane >= off) x += y;
    }
    if (lane == 63) wsum[w] = x;
    __syncthreads();
    int woff = 0;
    for (int i = 0; i < w; i++) woff += wsum[i];
    int run = woff + x - s;
#pragma unroll
    for (int i = 0; i < 4; i++){
        if (idx+i < n) excl[idx+i] = run;
        run += c[i];
    }
    if (t == 255) bsums[blockIdx.x] = woff + x;
}

__global__ void k_scan2(int* __restrict__ bsums, int nb){
    __shared__ int ws2[2];
    int t = threadIdx.x;
    int v = (t < nb) ? bsums[t] : 0;
    int lane = t & 63, w = t >> 6;
    int x = v;
#pragma unroll
    for (int off = 1; off < 64; off <<= 1){
        int y = __shfl_up(x, off);
        if (lane >= off) x += y;
    }
    if (lane == 63) ws2[w] = x;
    __syncthreads();
    int off0 = (w == 1) ? ws2[0] : 0;
    if (t < nb) bsums[t] = off0 + x - v;
}

__global__ void k_scan3(int* __restrict__ rp, const int* __restrict__ bsums,
                        int* __restrict__ fill, int n){
    int i = blockIdx.x*256 + threadIdx.x;
    if (i < n){
        int r = rp[i] + bsums[i >> 10];
        rp[i] = r;
        fill[i] = r;
    }
    if (i == 0) rp[n] = EE;
}

__global__ void k_place(const int* __restrict__ src, const int* __restrict__ dst,
                        int* __restrict__ fill, int* __restrict__ ssrc){
    int e = blockIdx.x*256 + threadIdx.x;
    if (e < EE){
        int p = atomicAdd(&fill[dst[e]], 1);
        ssrc[p] = src[e];
    }
}

// ---------------- graph rowptr from sorted batch ----------------
__global__ void k_bounds(const int* __restrict__ batch, int* __restrict__ rp_g){
    int i = blockIdx.x*256 + threadIdx.x;
    if (i >= NN) return;
    int b = batch[i];
    if (i == 0){
        for (int g = 0; g <= b; g++) rp_g[g] = 0;
    } else {
        int p = batch[i-1];
        for (int g = p+1; g <= b; g++) rp_g[g] = i;
    }
    if (i == NN-1){
        for (int g = b+1; g <= GG; g++) rp_g[g] = NN;
    }
}

// ---------------- W pre-swizzle into bf16 hi/lo B-fragment order ----------
// frag(kc, ct, l) at ((kc*8 + ct)*64 + l)*8 + j ; value W[kc*32+(l>>4)*8+j][ct*16+(l&15)]
__global__ void k_wprep(const float* __restrict__ W2_0, const float* __restrict__ W1s,
                        const float* __restrict__ W2s, short* __restrict__ Wp){
    int tid = blockIdx.x*256 + threadIdx.x;
    if (tid >= 9*16384) return;
    int m = tid >> 14;
    int r = tid & 16383;
    int j = r & 7, l = (r >> 3) & 63, ctkc = r >> 9;
    int ct = ctkc & 7, kc = ctkc >> 3;
    int k = kc*32 + ((l >> 4) << 3) + j;
    int n = (ct << 4) + (l & 15);
    const float* W = (m == 0) ? W2_0
                   : (m <= 4) ? (W1s + (size_t)(m-1)*HH*HH)
                              : (W2s + (size_t)(m-5)*HH*HH);
    float w = W[k*HH + n];
    short hi = f2bf(w);
    short lo = f2bf(w - bf2f(hi));
    short* base = Wp + (size_t)m*32768;
    base[r] = hi;
    base[16384 + r] = lo;
}

// ---------------- layer 0 aggregation (in=3) ----------------
__global__ void k_agg3(const float* __restrict__ x, const int* __restrict__ rp,
                       const int* __restrict__ ssrc, float* __restrict__ y){
    int i = blockIdx.x*256 + threadIdx.x;
    if (i >= NN) return;
    float a0 = x[3*i], a1 = x[3*i+1], a2 = x[3*i+2];
    int b = rp[i], e = rp[i+1];
    for (int k = b; k < e; k++){
        int s = ssrc[k];
        a0 += x[3*s]; a1 += x[3*s+1]; a2 += x[3*s+2];
    }
    y[3*i] = a0; y[3*i+1] = a1; y[3*i+2] = a2;
}

// ============ per-wave LDS layouts (no cross-wave sharing, NO barriers) ======
// bf16 planes (per wave: 4KB hi + 4KB lo):
//   element (row m in 0..15, col c): kc=c>>5, q=(c>>3)&3, j=c&7
//   chunk = (q<<4) | (m&8) | ((m&7) ^ ((q&1)<<2) ^ kc)
//   pos_short = kc*512 + chunk*8 + j
//   -> phase-2 b128 read: 8-lane groups hit 8 distinct 16B slots (conflict-free)
//   -> phase-1 b64 write: 2-way (free)
// fp32 plane (per wave: 8KB, union over bf16 planes):
//   chunkF(m2,q2) = (q2<<4) | ((m2>>2)<<2) | ((m2&3) ^ (((m2>>2)&1)<<1) ^ (q2&1))
//   pos_float = kc*512 + chunkF*8 + j
//   -> phase-3 b32 write conflict-free; phase-4 b128 read 2-way (free)

__device__ inline void wave_gemm(const short* __restrict__ sAh,
                                 const short* __restrict__ sAl,
                                 const short* __restrict__ Wp,
                                 int n, int q, f32x4* acc){
    const short* Wh = Wp;
    const short* Wl = Wp + 16384;
    const int l = (q << 4) | n;
#pragma unroll
    for (int ct = 0; ct < 8; ct++) acc[ct] = (f32x4){0.f,0.f,0.f,0.f};
#pragma unroll
    for (int kc = 0; kc < 4; kc++){
        int c = (q << 4) | (n & 8) | ((n & 7) ^ ((q & 1) << 2) ^ kc);
        int pos = kc*512 + c*8;
        bf16x8 ah = *(const bf16x8*)&sAh[pos];
        bf16x8 al = *(const bf16x8*)&sAl[pos];
        const short* ph = Wh + (size_t)(kc*8)*512 + l*8;
        const short* pl = Wl + (size_t)(kc*8)*512 + l*8;
#pragma unroll
        for (int ct = 0; ct < 8; ct++){
            bf16x8 bh = *(const bf16x8*)(ph + ct*512);
            bf16x8 bl = *(const bf16x8*)(pl + ct*512);
            acc[ct] = __builtin_amdgcn_mfma_f32_16x16x32_bf16(ah, bh, acc[ct], 0, 0, 0);
            acc[ct] = __builtin_amdgcn_mfma_f32_16x16x32_bf16(al, bh, acc[ct], 0, 0, 0);
            acc[ct] = __builtin_amdgcn_mfma_f32_16x16x32_bf16(ah, bl, acc[ct], 0, 0, 0);
        }
    }
}

// ---------------- layer 0 fused: mlp0 + GEMM(W2_0), per-wave, barrier-free ----
__global__ __launch_bounds__(256, 5)
void k_layer0(const float* __restrict__ y0, const short* __restrict__ Wp,
              const float* __restrict__ W1, const float* __restrict__ b1,
              const float* __restrict__ g, const float* __restrict__ be,
              const float* __restrict__ m, const float* __restrict__ v,
              const float* __restrict__ b2, float* __restrict__ out){
    __shared__ __align__(16) char smem[32768];
    const int t = threadIdx.x;
    const int w = t >> 6, l = t & 63;
    short* sAh = (short*)(smem + w*8192);
    short* sAl = (short*)(smem + w*8192 + 4096);
    const int R0 = blockIdx.x*64 + w*16;

    // phase 1: h1 = relu(BN(y0 @ W1 + b1)) for 4 cols, split -> own LDS quadrant
    {
        int hw = l >> 5, ln = l & 31;
        int c4 = ln << 2;
        int kc1 = ln >> 3, q1 = (ln >> 1) & 3, j1 = (ln & 1) << 2;
        float Wc[3][4], Ac[4], Bc[4];
#pragma unroll
        for (int i = 0; i < 4; i++){
            int c = c4 + i;
            float rs = rsqrtf(v[c] + 1e-5f);
            float sc = g[c]*rs;
            Ac[i] = sc;
            Bc[i] = sc*(b1[c] - m[c]) + be[c];
            Wc[0][i] = W1[c]; Wc[1][i] = W1[HH + c]; Wc[2][i] = W1[2*HH + c];
        }
        for (int it = 0; it < 8; it++){
            int mm = hw + (it << 1);
            int node = R0 + mm;
            float y0a = y0[3*node], y0b = y0[3*node+1], y0c = y0[3*node+2];
            float xs[4];
#pragma unroll
            for (int i = 0; i < 4; i++){
                float raw = y0a*Wc[0][i] + y0b*Wc[1][i] + y0c*Wc[2][i];
                xs[i] = fmaxf(fmaf(raw, Ac[i], Bc[i]), 0.f);
            }
            int c = (q1 << 4) | (mm & 8) | ((mm & 7) ^ ((q1 & 1) << 2) ^ kc1);
            int pos = kc1*512 + c*8 + j1;
            unsigned hp[2], lp[2];
#pragma unroll
            for (int i = 0; i < 2; i++){
                unsigned u0 = __float_as_uint(xs[2*i]);
                unsigned u1 = __float_as_uint(xs[2*i+1]);
                float r0 = xs[2*i]   - __uint_as_float(u0 & 0xFFFF0000u);
                float r1 = xs[2*i+1] - __uint_as_float(u1 & 0xFFFF0000u);
                hp[i] = (u0 >> 16) | (u1 & 0xFFFF0000u);
                lp[i] = (__float_as_uint(r0) >> 16) | (__float_as_uint(r1) & 0xFFFF0000u);
            }
            *(uint2*)&sAh[pos] = make_uint2(hp[0], hp[1]);
            *(uint2*)&sAl[pos] = make_uint2(lp[0], lp[1]);
        }
    }
    __asm__ volatile("" ::: "memory");

    // phase 2: GEMM vs W2_0, bias+relu epilogue (same-wave LDS, no barrier)
    const int n = l & 15, q = l >> 4;
    f32x4 acc[8];
    wave_gemm(sAh, sAl, Wp, n, q, acc);
#pragma unroll
    for (int ct = 0; ct < 8; ct++){
        int j = (ct << 4) + n;
        float shv = b2[j];
#pragma unroll
        for (int r = 0; r < 4; r++){
            int row = R0 + q*4 + r;
            out[(size_t)row*HH + j] = fmaxf(acc[ct][r] + shv, 0.f);
        }
    }
}

// ---------------- full GIN layer, per-wave tiles, barrier-free ----------------
__global__ __launch_bounds__(256, 5)
void k_layer(const float* __restrict__ A, const int* __restrict__ rp,
             const int* __restrict__ ssrc,
             const short* __restrict__ Wp1, const short* __restrict__ Wp2,
             const float* __restrict__ b1, const float* __restrict__ g,
             const float* __restrict__ be, const float* __restrict__ m,
             const float* __restrict__ v, const float* __restrict__ b2,
             float* __restrict__ out){
    __shared__ __align__(16) char smem[32768];
    const int t = threadIdx.x;
    const int w = t >> 6, l = t & 63;
    short* sAh = (short*)(smem + w*8192);
    short* sAl = (short*)(smem + w*8192 + 4096);
    float* sF  = (float*)(smem + w*8192);
    const int R0 = blockIdx.x*64 + w*16;

    // ---- phase 1: gather+sum 16 rows (2 per half-wave in flight), -> LDS ----
    {
        int hw = l >> 5, ln = l & 31;
        int c4 = ln << 2;
        int kc1 = ln >> 3, q1 = (ln >> 1) & 3, j1 = (ln & 1) << 2;
        const float* Ac = A + c4;
        for (int it = 0; it < 8; it++){
            int mm = hw + (it << 1);
            int node = R0 + mm;
            float4 a0 = *(const float4*)&Ac[(size_t)node*HH];
            if (node < NN){
                int b = rp[node], e = rp[node+1];
                float4 a1 = {0,0,0,0}, a2 = {0,0,0,0}, a3 = {0,0,0,0};
                int k = b;
                for (; k + 3 < e; k += 4){
                    int s0 = ssrc[k], s1 = ssrc[k+1], s2 = ssrc[k+2], s3 = ssrc[k+3];
                    float4 t0 = *(const float4*)&Ac[(size_t)s0*HH];
                    float4 t1 = *(const float4*)&Ac[(size_t)s1*HH];
                    float4 t2 = *(const float4*)&Ac[(size_t)s2*HH];
                    float4 t3 = *(const float4*)&Ac[(size_t)s3*HH];
                    a0.x+=t0.x; a0.y+=t0.y; a0.z+=t0.z; a0.w+=t0.w;
                    a1.x+=t1.x; a1.y+=t1.y; a1.z+=t1.z; a1.w+=t1.w;
                    a2.x+=t2.x; a2.y+=t2.y; a2.z+=t2.z; a2.w+=t2.w;
                    a3.x+=t3.x; a3.y+=t3.y; a3.z+=t3.z; a3.w+=t3.w;
                }
                if (k + 1 < e){
                    int s0 = ssrc[k], s1 = ssrc[k+1];
                    float4 t0 = *(const float4*)&Ac[(size_t)s0*HH];
                    float4 t1 = *(const float4*)&Ac[(size_t)s1*HH];
                    a0.x+=t0.x; a0.y+=t0.y; a0.z+=t0.z; a0.w+=t0.w;
                    a1.x+=t1.x; a1.y+=t1.y; a1.z+=t1.z; a1.w+=t1.w;
                    k += 2;
                }
                if (k < e){
                    int s0 = ssrc[k];
                    float4 t0 = *(const float4*)&Ac[(size_t)s0*HH];
                    a0.x+=t0.x; a0.y+=t0.y; a0.z+=t0.z; a0.w+=t0.w;
                }
                a0.x += a1.x+a2.x+a3.x; a0.y += a1.y+a2.y+a3.y;
                a0.z += a1.z+a2.z+a3.z; a0.w += a1.w+a2.w+a3.w;
            }
            int c = (q1 << 4) | (mm & 8) | ((mm & 7) ^ ((q1 & 1) << 2) ^ kc1);
            int pos = kc1*512 + c*8 + j1;
            float xs[4] = {a0.x, a0.y, a0.z, a0.w};
            unsigned hp[2], lp[2];
#pragma unroll
            for (int i = 0; i < 2; i++){
                unsigned u0 = __float_as_uint(xs[2*i]);
                unsigned u1 = __float_as_uint(xs[2*i+1]);
                float r0 = xs[2*i]   - __uint_as_float(u0 & 0xFFFF0000u);
                float r1 = xs[2*i+1] - __uint_as_float(u1 & 0xFFFF0000u);
                hp[i] = (u0 >> 16) | (u1 & 0xFFFF0000u);
                lp[i] = (__float_as_uint(r0) >> 16) | (__float_as_uint(r1) & 0xFFFF0000u);
            }
            *(uint2*)&sAh[pos] = make_uint2(hp[0], hp[1]);
            *(uint2*)&sAl[pos] = make_uint2(lp[0], lp[1]);
        }
    }
    __asm__ volatile("" ::: "memory");

    const int n = l & 15, q = l >> 4;

    // ---- phase 2: GEMM1 + BN/ReLU in regs (same-wave LDS, no barrier) ----
    f32x4 acc[8];
    wave_gemm(sAh, sAl, Wp1, n, q, acc);
    float val[8][4];
#pragma unroll
    for (int ct = 0; ct < 8; ct++){
        int j = (ct << 4) + n;
        float rr = rsqrtf(v[j] + 1e-5f);
        float scv = g[j]*rr;
        float shv = be[j] + scv*(b1[j] - m[j]);
#pragma unroll
        for (int r = 0; r < 4; r++)
            val[ct][r] = fmaxf(fmaf(acc[ct][r], scv, shv), 0.f);
    }
    __asm__ volatile("" ::: "memory");

    // ---- phase 3: fp32 intermediate into own LDS quadrant (union) ----
#pragma unroll
    for (int ct = 0; ct < 8; ct++){
        int kc = ct >> 1;
        int q2 = ((ct & 1) << 1) | (n >> 3);
        int j = n & 7;
#pragma unroll
        for (int r = 0; r < 4; r++){
            int chunkF = (q2 << 4) | (q << 2) | (r ^ ((q & 1) << 1) ^ (n >> 3));
            sF[kc*512 + chunkF*8 + j] = val[ct][r];
        }
    }
    __asm__ volatile("" ::: "memory");

    // ---- phase 4: read frags, split, GEMM2 + bias/ReLU -> global ----
    {
        const short* Wh = Wp2;
        const short* Wl = Wp2 + 16384;
        f32x4 acc2[8];
#pragma unroll
        for (int ct = 0; ct < 8; ct++) acc2[ct] = (f32x4){0.f,0.f,0.f,0.f};
#pragma unroll
        for (int kc = 0; kc < 4; kc++){
            int chunkF = (q << 4) | ((n >> 2) << 2)
                       | ((n & 3) ^ (((n >> 2) & 1) << 1) ^ (q & 1));
            int base = kc*512 + chunkF*8;
            float4 fa = *(const float4*)&sF[base];
            float4 fb = *(const float4*)&sF[base + 4];
            float xs[8] = {fa.x,fa.y,fa.z,fa.w,fb.x,fb.y,fb.z,fb.w};
            bf16x8 ah, al;
#pragma unroll
            for (int i = 0; i < 8; i++){
                unsigned u = __float_as_uint(xs[i]);
                ah[i] = (short)(u >> 16);
                float rv = xs[i] - __uint_as_float(u & 0xFFFF0000u);
                al[i] = (short)(__float_as_uint(rv) >> 16);
            }
            const short* ph = Wh + (size_t)(kc*8)*512 + l*8;
            const short* pl = Wl + (size_t)(kc*8)*512 + l*8;
#pragma unroll
            for (int ct = 0; ct < 8; ct++){
                bf16x8 bh = *(const bf16x8*)(ph + ct*512);
                bf16x8 bl = *(const bf16x8*)(pl + ct*512);
                acc2[ct] = __builtin_amdgcn_mfma_f32_16x16x32_bf16(ah, bh, acc2[ct], 0, 0, 0);
                acc2[ct] = __builtin_amdgcn_mfma_f32_16x16x32_bf16(al, bh, acc2[ct], 0, 0, 0);
                acc2[ct] = __builtin_amdgcn_mfma_f32_16x16x32_bf16(ah, bl, acc2[ct], 0, 0, 0);
            }
        }
#pragma unroll
        for (int ct = 0; ct < 8; ct++){
            int j = (ct << 4) + n;
            float shv = b2[j];
#pragma unroll
            for (int r = 0; r < 4; r++){
                int row = R0 + q*4 + r;
                out[(size_t)row*HH + j] = fmaxf(acc2[ct][r] + shv, 0.f);
            }
        }
    }
}

// ---------------- pooling + classifier: block per graph, no atomics ---------
__global__ void k_pool2(const float* __restrict__ h, const float* __restrict__ Wc,
                        const float* __restrict__ bc, const int* __restrict__ rp_g,
                        float* __restrict__ out){
    __shared__ float ws[4];
    int g = blockIdx.x, t = threadIdx.x;
    long beg = (long)rp_g[g]*HH, end = (long)rp_g[g+1]*HH;
    float s = 0.f;
    for (long i = beg + t; i < end; i += 256) s += h[i]*Wc[(int)(i & 127)];
    int lane = t & 63, w = t >> 6;
#pragma unroll
    for (int off = 32; off > 0; off >>= 1) s += __shfl_down(s, off);
    if (lane == 0) ws[w] = s;
    __syncthreads();
    if (t == 0) out[g] = bc[0] + ws[0] + ws[1] + ws[2] + ws[3];
}

extern "C" void kernel_launch(void* const* d_in, const int* in_sizes, int n_in,
                              void* d_out, int out_size, void* d_ws, size_t ws_size,
                              hipStream_t stream){
    const float* x     = (const float*)d_in[0];
    const int*   ei    = (const int*)d_in[1];
    const int*   batch = (const int*)d_in[2];
    const float* W1_0  = (const float*)d_in[3];
    const float* b1_0  = (const float*)d_in[4];
    const float* g_0   = (const float*)d_in[5];
    const float* be_0  = (const float*)d_in[6];
    const float* m_0   = (const float*)d_in[7];
    const float* v_0   = (const float*)d_in[8];
    const float* W2_0  = (const float*)d_in[9];
    const float* b2_0  = (const float*)d_in[10];
    const float* W1s   = (const float*)d_in[11];
    const float* b1s   = (const float*)d_in[12];
    const float* gs    = (const float*)d_in[13];
    const float* bes   = (const float*)d_in[14];
    const float* ms    = (const float*)d_in[15];
    const float* vs    = (const float*)d_in[16];
    const float* W2s   = (const float*)d_in[17];
    const float* b2s   = (const float*)d_in[18];
    const float* Wc    = (const float*)d_in[19];
    const float* bc    = (const float*)d_in[20];

    float* P0 = (float*)d_ws;
    float* P1 = P0 + (size_t)NPAD*HH;
    int* rp    = (int*)(P1 + (size_t)NPAD*HH);
    int* fill  = rp + (NN + 1);
    int* ssrc  = fill + NN;
    int* bsums = ssrc + EE;
    int* rp_g  = bsums + 128;
    size_t wp_off = (size_t)(rp_g + (GG + 1) - (int*)d_ws);
    wp_off = (wp_off + 3) & ~(size_t)3;
    short* Wp = (short*)((int*)d_ws + wp_off);

    const int* src = ei;
    const int* dst = ei + EE;

    // --- CSR build ---
    k_zero_i32<<<(NN+255)/256, 256, 0, stream>>>(fill, NN);
    k_hist<<<(EE+255)/256, 256, 0, stream>>>(dst, fill);
    k_scan1<<<98, 256, 0, stream>>>(fill, rp, bsums, NN);
    k_scan2<<<1, 128, 0, stream>>>(bsums, 98);
    k_scan3<<<(NN+255)/256, 256, 0, stream>>>(rp, bsums, fill, NN);
    k_place<<<(EE+255)/256, 256, 0, stream>>>(src, dst, fill, ssrc);

    // --- graph rowptr + weight pre-swizzle ---
    k_bounds<<<(NN+255)/256, 256, 0, stream>>>(batch, rp_g);
    k_wprep<<<(9*16384)/256, 256, 0, stream>>>(W2_0, W1s, W2s, Wp);

    // --- layer 0: agg3 -> fused mlp0+GEMM(W2_0) ---
    k_agg3<<<(NN+255)/256, 256, 0, stream>>>(x, rp, ssrc, P1);
    k_layer0<<<NBLK2, 256, 0, stream>>>(P1, Wp, W1_0, b1_0, g_0, be_0, m_0, v_0,
                                        b2_0, P0);

    // --- layers 1..4: one fused barrier-free kernel per layer ---
    float* cur = P0; float* oth = P1;
    for (int l = 0; l < 4; l++){
        k_layer<<<NBLK2, 256, 0, stream>>>(cur, rp, ssrc,
                                           Wp + (size_t)(1+l)*32768,
                                           Wp + (size_t)(5+l)*32768,
                                           b1s + l*HH, gs + l*HH, bes + l*HH,
                                           ms + l*HH, vs + l*HH, b2s + l*HH,
                                           oth);
        float* tmp = cur; cur = oth; oth = tmp;
    }

    // --- pooling + classifier (no atomics) ---
    k_pool2<<<GG, 256, 0, stream>>>(cur, Wc, bc, rp_g, (float*)d_out);
}

// Round 9
// 602.949 us; speedup vs baseline: 1.4511x; 1.0466x over previous
//
#include <hip/hip_runtime.h>

#define NN 100000
#define EE 600000
#define HH 128
#define GG 1000
#define NPAD 100096   // 1564 * 64
#define NBLK2 1564

typedef __attribute__((ext_vector_type(8))) short bf16x8;
typedef __attribute__((ext_vector_type(4))) float f32x4;

__device__ inline short f2bf(float x){
    unsigned u = __float_as_uint(x);
    unsigned r = (u + 0x7FFFu + ((u >> 16) & 1u)) >> 16;
    return (short)r;
}
__device__ inline float bf2f(short h){
    unsigned u = ((unsigned)(unsigned short)h) << 16;
    return __uint_as_float(u);
}

// ---------------- CSR build ----------------
__global__ void k_zero_i32(int* __restrict__ p, int n){
    int i = blockIdx.x*256 + threadIdx.x;
    if (i < n) p[i] = 0;
}

__global__ void k_hist(const int* __restrict__ dst, int* __restrict__ cnt){
    int e = blockIdx.x*256 + threadIdx.x;
    if (e < EE) atomicAdd(&cnt[dst[e]], 1);
}

__global__ void k_scan1(const int* __restrict__ cnt, int* __restrict__ excl,
                        int* __restrict__ bsums, int n){
    __shared__ int wsum[4];
    int t = threadIdx.x;
    int idx = blockIdx.x*1024 + t*4;
    int c[4];
#pragma unroll
    for (int i = 0; i < 4; i++) c[i] = (idx+i < n) ? cnt[idx+i] : 0;
    int s = c[0]+c[1]+c[2]+c[3];
    int lane = t & 63, w = t >> 6;
    int x = s;
#pragma unroll
    for (int off = 1; off < 64; off <<= 1){
        int y = __shfl_up(x, off);
        if (lane >= off) x += y;
    }
    if (lane == 63) wsum[w] = x;
    __syncthreads();
    int woff = 0;
    for (int i = 0; i < w; i++) woff += wsum[i];
    int run = woff + x - s;
#pragma unroll
    for (int i = 0; i < 4; i++){
        if (idx+i < n) excl[idx+i] = run;
        run += c[i];
    }
    if (t == 255) bsums[blockIdx.x] = woff + x;
}

__global__ void k_scan2(int* __restrict__ bsums, int nb){
    __shared__ int ws2[2];
    int t = threadIdx.x;
    int v = (t < nb) ? bsums[t] : 0;
    int lane = t & 63, w = t >> 6;
    int x = v;
#pragma unroll
    for (int off = 1; off < 64; off <<= 1){
        int y = __shfl_up(x, off);
        if (lane >= off) x += y;
    }
    if (lane == 63) ws2[w] = x;
    __syncthreads();
    int off0 = (w == 1) ? ws2[0] : 0;
    if (t < nb) bsums[t] = off0 + x - v;
}

__global__ void k_scan3(int* __restrict__ rp, const int* __restrict__ bsums,
                        int* __restrict__ fill, int n){
    int i = blockIdx.x*256 + threadIdx.x;
    if (i < n){
        int r = rp[i] + bsums[i >> 10];
        rp[i] = r;
        fill[i] = r;
    }
    if (i == 0) rp[n] = EE;
}

__global__ void k_place(const int* __restrict__ src, const int* __restrict__ dst,
                        int* __restrict__ fill, int* __restrict__ ssrc){
    int e = blockIdx.x*256 + threadIdx.x;
    if (e < EE){
        int p = atomicAdd(&fill[dst[e]], 1);
        ssrc[p] = src[e];
    }
}

// ---------------- graph rowptr from sorted batch ----------------
__global__ void k_bounds(const int* __restrict__ batch, int* __restrict__ rp_g){
    int i = blockIdx.x*256 + threadIdx.x;
    if (i >= NN) return;
    int b = batch[i];
    if (i == 0){
        for (int g = 0; g <= b; g++) rp_g[g] = 0;
    } else {
        int p = batch[i-1];
        for (int g = p+1; g <= b; g++) rp_g[g] = i;
    }
    if (i == NN-1){
        for (int g = b+1; g <= GG; g++) rp_g[g] = NN;
    }
}

// ---------------- W pre-swizzle into bf16 hi/lo B-fragment order ----------
__global__ void k_wprep(const float* __restrict__ W2_0, const float* __restrict__ W1s,
                        const float* __restrict__ W2s, short* __restrict__ Wp){
    int tid = blockIdx.x*256 + threadIdx.x;
    if (tid >= 9*16384) return;
    int m = tid >> 14;
    int r = tid & 16383;
    int j = r & 7, l = (r >> 3) & 63, ctkc = r >> 9;
    int ct = ctkc & 7, kc = ctkc >> 3;
    int k = kc*32 + ((l >> 4) << 3) + j;
    int n = (ct << 4) + (l & 15);
    const float* W = (m == 0) ? W2_0
                   : (m <= 4) ? (W1s + (size_t)(m-1)*HH*HH)
                              : (W2s + (size_t)(m-5)*HH*HH);
    float w = W[k*HH + n];
    short hi = f2bf(w);
    short lo = f2bf(w - bf2f(hi));
    short* base = Wp + (size_t)m*32768;
    base[r] = hi;
    base[16384 + r] = lo;
}

// ---------------- layer 0 aggregation (in=3) ----------------
__global__ void k_agg3(const float* __restrict__ x, const int* __restrict__ rp,
                       const int* __restrict__ ssrc, float* __restrict__ y){
    int i = blockIdx.x*256 + threadIdx.x;
    if (i >= NN) return;
    float a0 = x[3*i], a1 = x[3*i+1], a2 = x[3*i+2];
    int b = rp[i], e = rp[i+1];
    for (int k = b; k < e; k++){
        int s = ssrc[k];
        a0 += x[3*s]; a1 += x[3*s+1]; a2 += x[3*s+2];
    }
    y[3*i] = a0; y[3*i+1] = a1; y[3*i+2] = a2;
}

// ============ per-wave LDS layouts (no cross-wave sharing, NO barriers) ======
// bf16 planes (per wave: 4KB hi + 4KB lo):
//   element (row m in 0..15, col c): kc=c>>5, q=(c>>3)&3, j=c&7
//   chunk = (q<<4) | (m&8) | ((m&7) ^ ((q&1)<<2) ^ kc)
//   pos_short = kc*512 + chunk*8 + j
// fp32 plane (per wave: 8KB, union over bf16 planes):
//   chunkF(m2,q2) = (q2<<4) | ((m2>>2)<<2) | ((m2&3) ^ (((m2>>2)&1)<<1) ^ (q2&1))

__device__ inline void wave_gemm(const short* __restrict__ sAh,
                                 const short* __restrict__ sAl,
                                 const short* __restrict__ Wp,
                                 int n, int q, f32x4* acc){
    const short* Wh = Wp;
    const short* Wl = Wp + 16384;
    const int l = (q << 4) | n;
#pragma unroll
    for (int ct = 0; ct < 8; ct++) acc[ct] = (f32x4){0.f,0.f,0.f,0.f};
#pragma unroll
    for (int kc = 0; kc < 4; kc++){
        int c = (q << 4) | (n & 8) | ((n & 7) ^ ((q & 1) << 2) ^ kc);
        int pos = kc*512 + c*8;
        bf16x8 ah = *(const bf16x8*)&sAh[pos];
        bf16x8 al = *(const bf16x8*)&sAl[pos];
        const short* ph = Wh + (size_t)(kc*8)*512 + l*8;
        const short* pl = Wl + (size_t)(kc*8)*512 + l*8;
#pragma unroll
        for (int ct = 0; ct < 8; ct++){
            bf16x8 bh = *(const bf16x8*)(ph + ct*512);
            bf16x8 bl = *(const bf16x8*)(pl + ct*512);
            acc[ct] = __builtin_amdgcn_mfma_f32_16x16x32_bf16(ah, bh, acc[ct], 0, 0, 0);
            acc[ct] = __builtin_amdgcn_mfma_f32_16x16x32_bf16(al, bh, acc[ct], 0, 0, 0);
            acc[ct] = __builtin_amdgcn_mfma_f32_16x16x32_bf16(ah, bl, acc[ct], 0, 0, 0);
        }
    }
}

// ---------------- layer 0 fused: mlp0 + GEMM(W2_0), per-wave, barrier-free ----
__global__ __launch_bounds__(256, 5)
void k_layer0(const float* __restrict__ y0, const short* __restrict__ Wp,
              const float* __restrict__ W1, const float* __restrict__ b1,
              const float* __restrict__ g, const float* __restrict__ be,
              const float* __restrict__ m, const float* __restrict__ v,
              const float* __restrict__ b2, float* __restrict__ out){
    __shared__ __align__(16) char smem[32768];
    const int t = threadIdx.x;
    const int w = t >> 6, l = t & 63;
    short* sAh = (short*)(smem + w*8192);
    short* sAl = (short*)(smem + w*8192 + 4096);
    const int R0 = blockIdx.x*64 + w*16;

    // phase 1: h1 = relu(BN(y0 @ W1 + b1)) for 4 cols, split -> own LDS quadrant
    {
        int hw = l >> 5, ln = l & 31;
        int c4 = ln << 2;
        int kc1 = ln >> 3, q1 = (ln >> 1) & 3, j1 = (ln & 1) << 2;
        float Wc[3][4], Ac[4], Bc[4];
#pragma unroll
        for (int i = 0; i < 4; i++){
            int c = c4 + i;
            float rs = rsqrtf(v[c] + 1e-5f);
            float sc = g[c]*rs;
            Ac[i] = sc;
            Bc[i] = sc*(b1[c] - m[c]) + be[c];
            Wc[0][i] = W1[c]; Wc[1][i] = W1[HH + c]; Wc[2][i] = W1[2*HH + c];
        }
        for (int it = 0; it < 8; it++){
            int mm = hw + (it << 1);
            int node = R0 + mm;
            float y0a = y0[3*node], y0b = y0[3*node+1], y0c = y0[3*node+2];
            float xs[4];
#pragma unroll
            for (int i = 0; i < 4; i++){
                float raw = y0a*Wc[0][i] + y0b*Wc[1][i] + y0c*Wc[2][i];
                xs[i] = fmaxf(fmaf(raw, Ac[i], Bc[i]), 0.f);
            }
            int c = (q1 << 4) | (mm & 8) | ((mm & 7) ^ ((q1 & 1) << 2) ^ kc1);
            int pos = kc1*512 + c*8 + j1;
            unsigned hp[2], lp[2];
#pragma unroll
            for (int i = 0; i < 2; i++){
                unsigned u0 = __float_as_uint(xs[2*i]);
                unsigned u1 = __float_as_uint(xs[2*i+1]);
                float r0 = xs[2*i]   - __uint_as_float(u0 & 0xFFFF0000u);
                float r1 = xs[2*i+1] - __uint_as_float(u1 & 0xFFFF0000u);
                hp[i] = (u0 >> 16) | (u1 & 0xFFFF0000u);
                lp[i] = (__float_as_uint(r0) >> 16) | (__float_as_uint(r1) & 0xFFFF0000u);
            }
            *(uint2*)&sAh[pos] = make_uint2(hp[0], hp[1]);
            *(uint2*)&sAl[pos] = make_uint2(lp[0], lp[1]);
        }
    }
    __asm__ volatile("" ::: "memory");

    // phase 2: GEMM vs W2_0, bias+relu epilogue (same-wave LDS, no barrier)
    const int n = l & 15, q = l >> 4;
    f32x4 acc[8];
    wave_gemm(sAh, sAl, Wp, n, q, acc);
#pragma unroll
    for (int ct = 0; ct < 8; ct++){
        int j = (ct << 4) + n;
        float shv = b2[j];
#pragma unroll
        for (int r = 0; r < 4; r++){
            int row = R0 + q*4 + r;
            out[(size_t)row*HH + j] = fmaxf(acc[ct][r] + shv, 0.f);
        }
    }
}

// ---------------- full GIN layer, per-wave tiles, barrier-free ----------------
// phase 1 v2: quarter-wave (16 lanes) per row; lane owns 8 cols (two dwordx4
// per gather) -> 4 rows concurrently per wave, 8 loads in flight per qw.
__global__ __launch_bounds__(256, 5)
void k_layer(const float* __restrict__ A, const int* __restrict__ rp,
             const int* __restrict__ ssrc,
             const short* __restrict__ Wp1, const short* __restrict__ Wp2,
             const float* __restrict__ b1, const float* __restrict__ g,
             const float* __restrict__ be, const float* __restrict__ m,
             const float* __restrict__ v, const float* __restrict__ b2,
             float* __restrict__ out){
    __shared__ __align__(16) char smem[32768];
    const int t = threadIdx.x;
    const int w = t >> 6, l = t & 63;
    short* sAh = (short*)(smem + w*8192);
    short* sAl = (short*)(smem + w*8192 + 4096);
    float* sF  = (float*)(smem + w*8192);
    const int R0 = blockIdx.x*64 + w*16;

    // ---- phase 1: gather+sum 16 rows, 4 concurrent (one per quarter-wave) ----
    {
        int qw = l >> 4, ln = l & 15;
        int c8 = ln << 3;
        int kc1 = ln >> 2, q1 = ln & 3;
        const float* Ac = A + c8;
        for (int it = 0; it < 4; it++){
            int mm = qw + (it << 2);
            int node = R0 + mm;
            const float* rowp = &Ac[(size_t)node*HH];
            float4 xa = *(const float4*)rowp;
            float4 xb = *(const float4*)(rowp + 4);
            if (node < NN){
                int b = rp[node], e = rp[node+1];
                float4 a1={0,0,0,0}, a2={0,0,0,0}, a3={0,0,0,0};
                float4 c1={0,0,0,0}, c2={0,0,0,0}, c3={0,0,0,0};
                int k = b;
                for (; k + 3 < e; k += 4){
                    int s0=ssrc[k], s1=ssrc[k+1], s2=ssrc[k+2], s3=ssrc[k+3];
                    const float* p0=&Ac[(size_t)s0*HH];
                    const float* p1=&Ac[(size_t)s1*HH];
                    const float* p2=&Ac[(size_t)s2*HH];
                    const float* p3=&Ac[(size_t)s3*HH];
                    float4 t0a=*(const float4*)p0, t0b=*(const float4*)(p0+4);
                    float4 t1a=*(const float4*)p1, t1b=*(const float4*)(p1+4);
                    float4 t2a=*(const float4*)p2, t2b=*(const float4*)(p2+4);
                    float4 t3a=*(const float4*)p3, t3b=*(const float4*)(p3+4);
                    xa.x+=t0a.x; xa.y+=t0a.y; xa.z+=t0a.z; xa.w+=t0a.w;
                    xb.x+=t0b.x; xb.y+=t0b.y; xb.z+=t0b.z; xb.w+=t0b.w;
                    a1.x+=t1a.x; a1.y+=t1a.y; a1.z+=t1a.z; a1.w+=t1a.w;
                    c1.x+=t1b.x; c1.y+=t1b.y; c1.z+=t1b.z; c1.w+=t1b.w;
                    a2.x+=t2a.x; a2.y+=t2a.y; a2.z+=t2a.z; a2.w+=t2a.w;
                    c2.x+=t2b.x; c2.y+=t2b.y; c2.z+=t2b.z; c2.w+=t2b.w;
                    a3.x+=t3a.x; a3.y+=t3a.y; a3.z+=t3a.z; a3.w+=t3a.w;
                    c3.x+=t3b.x; c3.y+=t3b.y; c3.z+=t3b.z; c3.w+=t3b.w;
                }
                if (k + 1 < e){
                    int s0=ssrc[k], s1=ssrc[k+1];
                    const float* p0=&Ac[(size_t)s0*HH];
                    const float* p1=&Ac[(size_t)s1*HH];
                    float4 t0a=*(const float4*)p0, t0b=*(const float4*)(p0+4);
                    float4 t1a=*(const float4*)p1, t1b=*(const float4*)(p1+4);
                    xa.x+=t0a.x; xa.y+=t0a.y; xa.z+=t0a.z; xa.w+=t0a.w;
                    xb.x+=t0b.x; xb.y+=t0b.y; xb.z+=t0b.z; xb.w+=t0b.w;
                    a1.x+=t1a.x; a1.y+=t1a.y; a1.z+=t1a.z; a1.w+=t1a.w;
                    c1.x+=t1b.x; c1.y+=t1b.y; c1.z+=t1b.z; c1.w+=t1b.w;
                    k += 2;
                }
                if (k < e){
                    int s0=ssrc[k];
                    const float* p0=&Ac[(size_t)s0*HH];
                    float4 t0a=*(const float4*)p0, t0b=*(const float4*)(p0+4);
                    xa.x+=t0a.x; xa.y+=t0a.y; xa.z+=t0a.z; xa.w+=t0a.w;
                    xb.x+=t0b.x; xb.y+=t0b.y; xb.z+=t0b.z; xb.w+=t0b.w;
                }
                xa.x+=a1.x+a2.x+a3.x; xa.y+=a1.y+a2.y+a3.y;
                xa.z+=a1.z+a2.z+a3.z; xa.w+=a1.w+a2.w+a3.w;
                xb.x+=c1.x+c2.x+c3.x; xb.y+=c1.y+c2.y+c3.y;
                xb.z+=c1.z+c2.z+c3.z; xb.w+=c1.w+c2.w+c3.w;
            }
            int c = (q1 << 4) | (mm & 8) | ((mm & 7) ^ ((q1 & 1) << 2) ^ kc1);
            int pos = kc1*512 + c*8;
            float xs[8] = {xa.x,xa.y,xa.z,xa.w,xb.x,xb.y,xb.z,xb.w};
            unsigned hp[4], lp[4];
#pragma unroll
            for (int i = 0; i < 4; i++){
                unsigned u0 = __float_as_uint(xs[2*i]);
                unsigned u1 = __float_as_uint(xs[2*i+1]);
                float r0 = xs[2*i]   - __uint_as_float(u0 & 0xFFFF0000u);
                float r1 = xs[2*i+1] - __uint_as_float(u1 & 0xFFFF0000u);
                hp[i] = (u0 >> 16) | (u1 & 0xFFFF0000u);
                lp[i] = (__float_as_uint(r0) >> 16) | (__float_as_uint(r1) & 0xFFFF0000u);
            }
            *(uint4*)&sAh[pos] = make_uint4(hp[0], hp[1], hp[2], hp[3]);
            *(uint4*)&sAl[pos] = make_uint4(lp[0], lp[1], lp[2], lp[3]);
        }
    }
    __asm__ volatile("" ::: "memory");

    const int n = l & 15, q = l >> 4;

    // ---- phase 2: GEMM1; BN/ReLU epilogue written DIRECTLY to sF ----
    f32x4 acc[8];
    wave_gemm(sAh, sAl, Wp1, n, q, acc);
    __asm__ volatile("" ::: "memory");
#pragma unroll
    for (int ct = 0; ct < 8; ct++){
        int j = (ct << 4) + n;
        float rr = rsqrtf(v[j] + 1e-5f);
        float scv = g[j]*rr;
        float shv = be[j] + scv*(b1[j] - m[j]);
        int kc = ct >> 1;
        int q2 = ((ct & 1) << 1) | (n >> 3);
        int jj = n & 7;
#pragma unroll
        for (int r = 0; r < 4; r++){
            float vv = fmaxf(fmaf(acc[ct][r], scv, shv), 0.f);
            int chunkF = (q2 << 4) | (q << 2) | (r ^ ((q & 1) << 1) ^ (n >> 3));
            sF[kc*512 + chunkF*8 + jj] = vv;
        }
    }
    __asm__ volatile("" ::: "memory");

    // ---- phase 4: read frags, split, GEMM2 + bias/ReLU -> global (reuse acc) ----
    {
        const short* Wh = Wp2;
        const short* Wl = Wp2 + 16384;
#pragma unroll
        for (int ct = 0; ct < 8; ct++) acc[ct] = (f32x4){0.f,0.f,0.f,0.f};
#pragma unroll
        for (int kc = 0; kc < 4; kc++){
            int chunkF = (q << 4) | ((n >> 2) << 2)
                       | ((n & 3) ^ (((n >> 2) & 1) << 1) ^ (q & 1));
            int base = kc*512 + chunkF*8;
            float4 fa = *(const float4*)&sF[base];
            float4 fb = *(const float4*)&sF[base + 4];
            float xs[8] = {fa.x,fa.y,fa.z,fa.w,fb.x,fb.y,fb.z,fb.w};
            bf16x8 ah, al;
#pragma unroll
            for (int i = 0; i < 8; i++){
                unsigned u = __float_as_uint(xs[i]);
                ah[i] = (short)(u >> 16);
                float rv = xs[i] - __uint_as_float(u & 0xFFFF0000u);
                al[i] = (short)(__float_as_uint(rv) >> 16);
            }
            const short* ph = Wh + (size_t)(kc*8)*512 + l*8;
            const short* pl = Wl + (size_t)(kc*8)*512 + l*8;
#pragma unroll
            for (int ct = 0; ct < 8; ct++){
                bf16x8 bh = *(const bf16x8*)(ph + ct*512);
                bf16x8 bl = *(const bf16x8*)(pl + ct*512);
                acc[ct] = __builtin_amdgcn_mfma_f32_16x16x32_bf16(ah, bh, acc[ct], 0, 0, 0);
                acc[ct] = __builtin_amdgcn_mfma_f32_16x16x32_bf16(al, bh, acc[ct], 0, 0, 0);
                acc[ct] = __builtin_amdgcn_mfma_f32_16x16x32_bf16(ah, bl, acc[ct], 0, 0, 0);
            }
        }
#pragma unroll
        for (int ct = 0; ct < 8; ct++){
            int j = (ct << 4) + n;
            float shv = b2[j];
#pragma unroll
            for (int r = 0; r < 4; r++){
                int row = R0 + q*4 + r;
                out[(size_t)row*HH + j] = fmaxf(acc[ct][r] + shv, 0.f);
            }
        }
    }
}

// ---------------- pooling + classifier: block per graph, no atomics ---------
__global__ void k_pool2(const float* __restrict__ h, const float* __restrict__ Wc,
                        const float* __restrict__ bc, const int* __restrict__ rp_g,
                        float* __restrict__ out){
    __shared__ float ws[4];
    int g = blockIdx.x, t = threadIdx.x;
    long beg = (long)rp_g[g]*HH, end = (long)rp_g[g+1]*HH;
    float s = 0.f;
    for (long i = beg + t; i < end; i += 256) s += h[i]*Wc[(int)(i & 127)];
    int lane = t & 63, w = t >> 6;
#pragma unroll
    for (int off = 32; off > 0; off >>= 1) s += __shfl_down(s, off);
    if (lane == 0) ws[w] = s;
    __syncthreads();
    if (t == 0) out[g] = bc[0] + ws[0] + ws[1] + ws[2] + ws[3];
}

extern "C" void kernel_launch(void* const* d_in, const int* in_sizes, int n_in,
                              void* d_out, int out_size, void* d_ws, size_t ws_size,
                              hipStream_t stream){
    const float* x     = (const float*)d_in[0];
    const int*   ei    = (const int*)d_in[1];
    const int*   batch = (const int*)d_in[2];
    const float* W1_0  = (const float*)d_in[3];
    const float* b1_0  = (const float*)d_in[4];
    const float* g_0   = (const float*)d_in[5];
    const float* be_0  = (const float*)d_in[6];
    const float* m_0   = (const float*)d_in[7];
    const float* v_0   = (const float*)d_in[8];
    const float* W2_0  = (const float*)d_in[9];
    const float* b2_0  = (const float*)d_in[10];
    const float* W1s   = (const float*)d_in[11];
    const float* b1s   = (const float*)d_in[12];
    const float* gs    = (const float*)d_in[13];
    const float* bes   = (const float*)d_in[14];
    const float* ms    = (const float*)d_in[15];
    const float* vs    = (const float*)d_in[16];
    const float* W2s   = (const float*)d_in[17];
    const float* b2s   = (const float*)d_in[18];
    const float* Wc    = (const float*)d_in[19];
    const float* bc    = (const float*)d_in[20];

    float* P0 = (float*)d_ws;
    float* P1 = P0 + (size_t)NPAD*HH;
    int* rp    = (int*)(P1 + (size_t)NPAD*HH);
    int* fill  = rp + (NN + 1);
    int* ssrc  = fill + NN;
    int* bsums = ssrc + EE;
    int* rp_g  = bsums + 128;
    size_t wp_off = (size_t)(rp_g + (GG + 1) - (int*)d_ws);
    wp_off = (wp_off + 3) & ~(size_t)3;
    short* Wp = (short*)((int*)d_ws + wp_off);

    const int* src = ei;
    const int* dst = ei + EE;

    // --- CSR build ---
    k_zero_i32<<<(NN+255)/256, 256, 0, stream>>>(fill, NN);
    k_hist<<<(EE+255)/256, 256, 0, stream>>>(dst, fill);
    k_scan1<<<98, 256, 0, stream>>>(fill, rp, bsums, NN);
    k_scan2<<<1, 128, 0, stream>>>(bsums, 98);
    k_scan3<<<(NN+255)/256, 256, 0, stream>>>(rp, bsums, fill, NN);
    k_place<<<(EE+255)/256, 256, 0, stream>>>(src, dst, fill, ssrc);

    // --- graph rowptr + weight pre-swizzle ---
    k_bounds<<<(NN+255)/256, 256, 0, stream>>>(batch, rp_g);
    k_wprep<<<(9*16384)/256, 256, 0, stream>>>(W2_0, W1s, W2s, Wp);

    // --- layer 0: agg3 -> fused mlp0+GEMM(W2_0) ---
    k_agg3<<<(NN+255)/256, 256, 0, stream>>>(x, rp, ssrc, P1);
    k_layer0<<<NBLK2, 256, 0, stream>>>(P1, Wp, W1_0, b1_0, g_0, be_0, m_0, v_0,
                                        b2_0, P0);

    // --- layers 1..4: one fused barrier-free kernel per layer ---
    float* cur = P0; float* oth = P1;
    for (int l = 0; l < 4; l++){
        k_layer<<<NBLK2, 256, 0, stream>>>(cur, rp, ssrc,
                                           Wp + (size_t)(1+l)*32768,
                                           Wp + (size_t)(5+l)*32768,
                                           b1s + l*HH, gs + l*HH, bes + l*HH,
                                           ms + l*HH, vs + l*HH, b2s + l*HH,
                                           oth);
        float* tmp = cur; cur = oth; oth = tmp;
    }

    // --- pooling + classifier (no atomics) ---
    k_pool2<<<GG, 256, 0, stream>>>(cur, Wc, bc, rp_g, (float*)d_out);
}

// Round 10
// 547.637 us; speedup vs baseline: 1.5977x; 1.1010x over previous
//
#include <hip/hip_runtime.h>

#define NN 100000
#define EE 600000
#define HH 128
#define GG 1000
#define NPAD 100096   // 1564 * 64
#define NBLK2 1564

typedef __attribute__((ext_vector_type(8))) short bf16x8;
typedef __attribute__((ext_vector_type(4))) float f32x4;

__device__ inline short f2bf(float x){
    unsigned u = __float_as_uint(x);
    unsigned r = (u + 0x7FFFu + ((u >> 16) & 1u)) >> 16;
    return (short)r;
}
__device__ inline float bf2f(short h){
    unsigned u = ((unsigned)(unsigned short)h) << 16;
    return __uint_as_float(u);
}

// ---------------- CSR build ----------------
__global__ void k_hist(const int* __restrict__ dst, int* __restrict__ cnt){
    int e = blockIdx.x*256 + threadIdx.x;
    if (e < EE) atomicAdd(&cnt[dst[e]], 1);
}

__global__ void k_scan1(const int* __restrict__ cnt, int* __restrict__ excl,
                        int* __restrict__ bsums, int n){
    __shared__ int wsum[4];
    int t = threadIdx.x;
    int idx = blockIdx.x*1024 + t*4;
    int c[4];
#pragma unroll
    for (int i = 0; i < 4; i++) c[i] = (idx+i < n) ? cnt[idx+i] : 0;
    int s = c[0]+c[1]+c[2]+c[3];
    int lane = t & 63, w = t >> 6;
    int x = s;
#pragma unroll
    for (int off = 1; off < 64; off <<= 1){
        int y = __shfl_up(x, off);
        if (lane >= off) x += y;
    }
    if (lane == 63) wsum[w] = x;
    __syncthreads();
    int woff = 0;
    for (int i = 0; i < w; i++) woff += wsum[i];
    int run = woff + x - s;
#pragma unroll
    for (int i = 0; i < 4; i++){
        if (idx+i < n) excl[idx+i] = run;
        run += c[i];
    }
    if (t == 255) bsums[blockIdx.x] = woff + x;
}

__global__ void k_scan2(int* __restrict__ bsums, int nb){
    __shared__ int ws2[2];
    int t = threadIdx.x;
    int v = (t < nb) ? bsums[t] : 0;
    int lane = t & 63, w = t >> 6;
    int x = v;
#pragma unroll
    for (int off = 1; off < 64; off <<= 1){
        int y = __shfl_up(x, off);
        if (lane >= off) x += y;
    }
    if (lane == 63) ws2[w] = x;
    __syncthreads();
    int off0 = (w == 1) ? ws2[0] : 0;
    if (t < nb) bsums[t] = off0 + x - v;
}

__global__ void k_scan3(int* __restrict__ rp, const int* __restrict__ bsums,
                        int* __restrict__ fill, int n){
    int i = blockIdx.x*256 + threadIdx.x;
    if (i < n){
        int r = rp[i] + bsums[i >> 10];
        rp[i] = r;
        fill[i] = r;
    }
    if (i == 0) rp[n] = EE;
}

__global__ void k_place(const int* __restrict__ src, const int* __restrict__ dst,
                        int* __restrict__ fill, int* __restrict__ ssrc){
    int e = blockIdx.x*256 + threadIdx.x;
    if (e < EE){
        int p = atomicAdd(&fill[dst[e]], 1);
        ssrc[p] = src[e];
    }
}

// ---------------- init: zero fill + graph rowptr + W pre-swizzle (merged) ----
__global__ void k_init(const int* __restrict__ batch, int* __restrict__ fill,
                       int* __restrict__ rp_g,
                       const float* __restrict__ W2_0, const float* __restrict__ W1s,
                       const float* __restrict__ W2s, short* __restrict__ Wp){
    int tid = blockIdx.x*256 + threadIdx.x;
    if (tid < NN){
        fill[tid] = 0;
        int b = batch[tid];
        if (tid == 0){
            for (int g = 0; g <= b; g++) rp_g[g] = 0;
        } else {
            int p = batch[tid-1];
            for (int g = p+1; g <= b; g++) rp_g[g] = tid;
        }
        if (tid == NN-1){
            for (int g = b+1; g <= GG; g++) rp_g[g] = NN;
        }
    }
    if (tid < 9*16384){
        int m = tid >> 14;
        int r = tid & 16383;
        int j = r & 7, l = (r >> 3) & 63, ctkc = r >> 9;
        int ct = ctkc & 7, kc = ctkc >> 3;
        int k = kc*32 + ((l >> 4) << 3) + j;
        int n = (ct << 4) + (l & 15);
        const float* W = (m == 0) ? W2_0
                       : (m <= 4) ? (W1s + (size_t)(m-1)*HH*HH)
                                  : (W2s + (size_t)(m-5)*HH*HH);
        float w = W[k*HH + n];
        short hi = f2bf(w);
        short lo = f2bf(w - bf2f(hi));
        short* base = Wp + (size_t)m*32768;
        base[r] = hi;
        base[16384 + r] = lo;
    }
}

// ---------------- layer 0 aggregation (in=3) ----------------
__global__ void k_agg3(const float* __restrict__ x, const int* __restrict__ rp,
                       const int* __restrict__ ssrc, float* __restrict__ y){
    int i = blockIdx.x*256 + threadIdx.x;
    if (i >= NN) return;
    float a0 = x[3*i], a1 = x[3*i+1], a2 = x[3*i+2];
    int b = rp[i], e = rp[i+1];
    for (int k = b; k < e; k++){
        int s = ssrc[k];
        a0 += x[3*s]; a1 += x[3*s+1]; a2 += x[3*s+2];
    }
    y[3*i] = a0; y[3*i+1] = a1; y[3*i+2] = a2;
}

// ============ per-wave LDS layouts (no cross-wave sharing, NO barriers) ======
// bf16 planes (per wave: 4KB hi + 4KB lo):
//   chunk = (q<<4) | (m&8) | ((m&7) ^ ((q&1)<<2) ^ kc); pos = kc*512 + chunk*8 + j
// fp32 plane (per wave: 8KB, union):
//   chunkF(m2,q2) = (q2<<4) | ((m2>>2)<<2) | ((m2&3) ^ (((m2>>2)&1)<<1) ^ (q2&1))

__device__ inline void wave_gemm(const short* __restrict__ sAh,
                                 const short* __restrict__ sAl,
                                 const short* __restrict__ Wp,
                                 int n, int q, f32x4* acc){
    const short* Wh = Wp;
    const short* Wl = Wp + 16384;
    const int l = (q << 4) | n;
#pragma unroll
    for (int ct = 0; ct < 8; ct++) acc[ct] = (f32x4){0.f,0.f,0.f,0.f};
#pragma unroll
    for (int kc = 0; kc < 4; kc++){
        int c = (q << 4) | (n & 8) | ((n & 7) ^ ((q & 1) << 2) ^ kc);
        int pos = kc*512 + c*8;
        bf16x8 ah = *(const bf16x8*)&sAh[pos];
        bf16x8 al = *(const bf16x8*)&sAl[pos];
        const short* ph = Wh + (size_t)(kc*8)*512 + l*8;
        const short* pl = Wl + (size_t)(kc*8)*512 + l*8;
#pragma unroll
        for (int ct = 0; ct < 8; ct++){
            bf16x8 bh = *(const bf16x8*)(ph + ct*512);
            bf16x8 bl = *(const bf16x8*)(pl + ct*512);
            acc[ct] = __builtin_amdgcn_mfma_f32_16x16x32_bf16(ah, bh, acc[ct], 0, 0, 0);
            acc[ct] = __builtin_amdgcn_mfma_f32_16x16x32_bf16(al, bh, acc[ct], 0, 0, 0);
            acc[ct] = __builtin_amdgcn_mfma_f32_16x16x32_bf16(ah, bl, acc[ct], 0, 0, 0);
        }
    }
}

// ---------------- layer 0 fused: mlp0 + GEMM(W2_0), per-wave, barrier-free ----
__global__ __launch_bounds__(256, 4)
void k_layer0(const float* __restrict__ y0, const short* __restrict__ Wp,
              const float* __restrict__ W1, const float* __restrict__ b1,
              const float* __restrict__ g, const float* __restrict__ be,
              const float* __restrict__ m, const float* __restrict__ v,
              const float* __restrict__ b2, float* __restrict__ out){
    __shared__ __align__(16) char smem[32768];
    const int t = threadIdx.x;
    const int w = t >> 6, l = t & 63;
    short* sAh = (short*)(smem + w*8192);
    short* sAl = (short*)(smem + w*8192 + 4096);
    const int R0 = blockIdx.x*64 + w*16;

    // phase 1: h1 = relu(BN(y0 @ W1 + b1)) for 4 cols, split -> own LDS quadrant
    {
        int hw = l >> 5, ln = l & 31;
        int c4 = ln << 2;
        int kc1 = ln >> 3, q1 = (ln >> 1) & 3, j1 = (ln & 1) << 2;
        float Wc[3][4], Ac[4], Bc[4];
#pragma unroll
        for (int i = 0; i < 4; i++){
            int c = c4 + i;
            float rs = rsqrtf(v[c] + 1e-5f);
            float sc = g[c]*rs;
            Ac[i] = sc;
            Bc[i] = sc*(b1[c] - m[c]) + be[c];
            Wc[0][i] = W1[c]; Wc[1][i] = W1[HH + c]; Wc[2][i] = W1[2*HH + c];
        }
        float ya[8], yb[8], yc[8];
#pragma unroll
        for (int it = 0; it < 8; it++){
            int node = R0 + hw + (it << 1);
            ya[it] = y0[3*node]; yb[it] = y0[3*node+1]; yc[it] = y0[3*node+2];
        }
#pragma unroll
        for (int it = 0; it < 8; it++){
            int mm = hw + (it << 1);
            float xs[4];
#pragma unroll
            for (int i = 0; i < 4; i++){
                float raw = ya[it]*Wc[0][i] + yb[it]*Wc[1][i] + yc[it]*Wc[2][i];
                xs[i] = fmaxf(fmaf(raw, Ac[i], Bc[i]), 0.f);
            }
            int c = (q1 << 4) | (mm & 8) | ((mm & 7) ^ ((q1 & 1) << 2) ^ kc1);
            int pos = kc1*512 + c*8 + j1;
            unsigned hp[2], lp[2];
#pragma unroll
            for (int i = 0; i < 2; i++){
                unsigned u0 = __float_as_uint(xs[2*i]);
                unsigned u1 = __float_as_uint(xs[2*i+1]);
                float r0 = xs[2*i]   - __uint_as_float(u0 & 0xFFFF0000u);
                float r1 = xs[2*i+1] - __uint_as_float(u1 & 0xFFFF0000u);
                hp[i] = (u0 >> 16) | (u1 & 0xFFFF0000u);
                lp[i] = (__float_as_uint(r0) >> 16) | (__float_as_uint(r1) & 0xFFFF0000u);
            }
            *(uint2*)&sAh[pos] = make_uint2(hp[0], hp[1]);
            *(uint2*)&sAl[pos] = make_uint2(lp[0], lp[1]);
        }
    }
    __asm__ volatile("" ::: "memory");

    const int n = l & 15, q = l >> 4;
    f32x4 acc[8];
    wave_gemm(sAh, sAl, Wp, n, q, acc);
#pragma unroll
    for (int ct = 0; ct < 8; ct++){
        int j = (ct << 4) + n;
        float shv = b2[j];
#pragma unroll
        for (int r = 0; r < 4; r++){
            int row = R0 + q*4 + r;
            out[(size_t)row*HH + j] = fmaxf(acc[ct][r] + shv, 0.f);
        }
    }
}

// ---------------- full GIN layer, per-wave tiles, barrier-free ----------------
// phase 1: quarter-wave per row, 4 rows concurrent per wave; self-loads and
// rp bounds for all 4 rows hoisted up front (cross-row pipelining).
__global__ __launch_bounds__(256, 4)
void k_layer(const float* __restrict__ A, const int* __restrict__ rp,
             const int* __restrict__ ssrc,
             const short* __restrict__ Wp1, const short* __restrict__ Wp2,
             const float* __restrict__ b1, const float* __restrict__ g,
             const float* __restrict__ be, const float* __restrict__ m,
             const float* __restrict__ v, const float* __restrict__ b2,
             float* __restrict__ out){
    __shared__ __align__(16) char smem[32768];
    const int t = threadIdx.x;
    const int w = t >> 6, l = t & 63;
    short* sAh = (short*)(smem + w*8192);
    short* sAl = (short*)(smem + w*8192 + 4096);
    float* sF  = (float*)(smem + w*8192);
    const int R0 = blockIdx.x*64 + w*16;

    // ---- phase 1 ----
    {
        int qw = l >> 4, ln = l & 15;
        int c8 = ln << 3;
        int kc1 = ln >> 2, q1 = ln & 3;
        const float* Ac = A + c8;

        // hoisted: self rows + CSR bounds for all 4 rows of this quarter-wave
        float4 sxa[4], sxb[4];
        int rb[4], re2[4];
#pragma unroll
        for (int it = 0; it < 4; it++){
            int node = R0 + qw + (it << 2);
            const float* rowp = &Ac[(size_t)node*HH];
            sxa[it] = *(const float4*)rowp;
            sxb[it] = *(const float4*)(rowp + 4);
            int nn = (node < NN) ? node : (NN - 1);
            rb[it] = rp[nn]; re2[it] = (node < NN) ? rp[nn+1] : rb[it];
        }

#pragma unroll
        for (int it = 0; it < 4; it++){
            int mm = qw + (it << 2);
            float4 xa = sxa[it], xb = sxb[it];
            int b = rb[it], e = re2[it];
            {
                float4 a1={0,0,0,0}, a2={0,0,0,0}, a3={0,0,0,0};
                float4 c1={0,0,0,0}, c2={0,0,0,0}, c3={0,0,0,0};
                int k = b;
                for (; k + 3 < e; k += 4){
                    int s0=ssrc[k], s1=ssrc[k+1], s2=ssrc[k+2], s3=ssrc[k+3];
                    const float* p0=&Ac[(size_t)s0*HH];
                    const float* p1=&Ac[(size_t)s1*HH];
                    const float* p2=&Ac[(size_t)s2*HH];
                    const float* p3=&Ac[(size_t)s3*HH];
                    float4 t0a=*(const float4*)p0, t0b=*(const float4*)(p0+4);
                    float4 t1a=*(const float4*)p1, t1b=*(const float4*)(p1+4);
                    float4 t2a=*(const float4*)p2, t2b=*(const float4*)(p2+4);
                    float4 t3a=*(const float4*)p3, t3b=*(const float4*)(p3+4);
                    xa.x+=t0a.x; xa.y+=t0a.y; xa.z+=t0a.z; xa.w+=t0a.w;
                    xb.x+=t0b.x; xb.y+=t0b.y; xb.z+=t0b.z; xb.w+=t0b.w;
                    a1.x+=t1a.x; a1.y+=t1a.y; a1.z+=t1a.z; a1.w+=t1a.w;
                    c1.x+=t1b.x; c1.y+=t1b.y; c1.z+=t1b.z; c1.w+=t1b.w;
                    a2.x+=t2a.x; a2.y+=t2a.y; a2.z+=t2a.z; a2.w+=t2a.w;
                    c2.x+=t2b.x; c2.y+=t2b.y; c2.z+=t2b.z; c2.w+=t2b.w;
                    a3.x+=t3a.x; a3.y+=t3a.y; a3.z+=t3a.z; a3.w+=t3a.w;
                    c3.x+=t3b.x; c3.y+=t3b.y; c3.z+=t3b.z; c3.w+=t3b.w;
                }
                if (k + 1 < e){
                    int s0=ssrc[k], s1=ssrc[k+1];
                    const float* p0=&Ac[(size_t)s0*HH];
                    const float* p1=&Ac[(size_t)s1*HH];
                    float4 t0a=*(const float4*)p0, t0b=*(const float4*)(p0+4);
                    float4 t1a=*(const float4*)p1, t1b=*(const float4*)(p1+4);
                    xa.x+=t0a.x; xa.y+=t0a.y; xa.z+=t0a.z; xa.w+=t0a.w;
                    xb.x+=t0b.x; xb.y+=t0b.y; xb.z+=t0b.z; xb.w+=t0b.w;
                    a1.x+=t1a.x; a1.y+=t1a.y; a1.z+=t1a.z; a1.w+=t1a.w;
                    c1.x+=t1b.x; c1.y+=t1b.y; c1.z+=t1b.z; c1.w+=t1b.w;
                    k += 2;
                }
                if (k < e){
                    int s0=ssrc[k];
                    const float* p0=&Ac[(size_t)s0*HH];
                    float4 t0a=*(const float4*)p0, t0b=*(const float4*)(p0+4);
                    xa.x+=t0a.x; xa.y+=t0a.y; xa.z+=t0a.z; xa.w+=t0a.w;
                    xb.x+=t0b.x; xb.y+=t0b.y; xb.z+=t0b.z; xb.w+=t0b.w;
                }
                xa.x+=a1.x+a2.x+a3.x; xa.y+=a1.y+a2.y+a3.y;
                xa.z+=a1.z+a2.z+a3.z; xa.w+=a1.w+a2.w+a3.w;
                xb.x+=c1.x+c2.x+c3.x; xb.y+=c1.y+c2.y+c3.y;
                xb.z+=c1.z+c2.z+c3.z; xb.w+=c1.w+c2.w+c3.w;
            }
            int c = (q1 << 4) | (mm & 8) | ((mm & 7) ^ ((q1 & 1) << 2) ^ kc1);
            int pos = kc1*512 + c*8;
            float xs[8] = {xa.x,xa.y,xa.z,xa.w,xb.x,xb.y,xb.z,xb.w};
            unsigned hp[4], lp[4];
#pragma unroll
            for (int i = 0; i < 4; i++){
                unsigned u0 = __float_as_uint(xs[2*i]);
                unsigned u1 = __float_as_uint(xs[2*i+1]);
                float r0 = xs[2*i]   - __uint_as_float(u0 & 0xFFFF0000u);
                float r1 = xs[2*i+1] - __uint_as_float(u1 & 0xFFFF0000u);
                hp[i] = (u0 >> 16) | (u1 & 0xFFFF0000u);
                lp[i] = (__float_as_uint(r0) >> 16) | (__float_as_uint(r1) & 0xFFFF0000u);
            }
            *(uint4*)&sAh[pos] = make_uint4(hp[0], hp[1], hp[2], hp[3]);
            *(uint4*)&sAl[pos] = make_uint4(lp[0], lp[1], lp[2], lp[3]);
        }
    }
    __asm__ volatile("" ::: "memory");

    const int n = l & 15, q = l >> 4;

    // ---- phase 2: GEMM1; BN/ReLU epilogue written DIRECTLY to sF ----
    f32x4 acc[8];
    wave_gemm(sAh, sAl, Wp1, n, q, acc);
    __asm__ volatile("" ::: "memory");
#pragma unroll
    for (int ct = 0; ct < 8; ct++){
        int j = (ct << 4) + n;
        float rr = rsqrtf(v[j] + 1e-5f);
        float scv = g[j]*rr;
        float shv = be[j] + scv*(b1[j] - m[j]);
        int kc = ct >> 1;
        int q2 = ((ct & 1) << 1) | (n >> 3);
        int jj = n & 7;
#pragma unroll
        for (int r = 0; r < 4; r++){
            float vv = fmaxf(fmaf(acc[ct][r], scv, shv), 0.f);
            int chunkF = (q2 << 4) | (q << 2) | (r ^ ((q & 1) << 1) ^ (n >> 3));
            sF[kc*512 + chunkF*8 + jj] = vv;
        }
    }
    __asm__ volatile("" ::: "memory");

    // ---- phase 4: read frags, split, GEMM2 + bias/ReLU -> global (reuse acc) ----
    {
        const short* Wh = Wp2;
        const short* Wl = Wp2 + 16384;
#pragma unroll
        for (int ct = 0; ct < 8; ct++) acc[ct] = (f32x4){0.f,0.f,0.f,0.f};
#pragma unroll
        for (int kc = 0; kc < 4; kc++){
            int chunkF = (q << 4) | ((n >> 2) << 2)
                       | ((n & 3) ^ (((n >> 2) & 1) << 1) ^ (q & 1));
            int base = kc*512 + chunkF*8;
            float4 fa = *(const float4*)&sF[base];
            float4 fb = *(const float4*)&sF[base + 4];
            float xs[8] = {fa.x,fa.y,fa.z,fa.w,fb.x,fb.y,fb.z,fb.w};
            bf16x8 ah, al;
#pragma unroll
            for (int i = 0; i < 8; i++){
                unsigned u = __float_as_uint(xs[i]);
                ah[i] = (short)(u >> 16);
                float rv = xs[i] - __uint_as_float(u & 0xFFFF0000u);
                al[i] = (short)(__float_as_uint(rv) >> 16);
            }
            const short* ph = Wh + (size_t)(kc*8)*512 + l*8;
            const short* pl = Wl + (size_t)(kc*8)*512 + l*8;
#pragma unroll
            for (int ct = 0; ct < 8; ct++){
                bf16x8 bh = *(const bf16x8*)(ph + ct*512);
                bf16x8 bl = *(const bf16x8*)(pl + ct*512);
                acc[ct] = __builtin_amdgcn_mfma_f32_16x16x32_bf16(ah, bh, acc[ct], 0, 0, 0);
                acc[ct] = __builtin_amdgcn_mfma_f32_16x16x32_bf16(al, bh, acc[ct], 0, 0, 0);
                acc[ct] = __builtin_amdgcn_mfma_f32_16x16x32_bf16(ah, bl, acc[ct], 0, 0, 0);
            }
        }
#pragma unroll
        for (int ct = 0; ct < 8; ct++){
            int j = (ct << 4) + n;
            float shv = b2[j];
#pragma unroll
            for (int r = 0; r < 4; r++){
                int row = R0 + q*4 + r;
                out[(size_t)row*HH + j] = fmaxf(acc[ct][r] + shv, 0.f);
            }
        }
    }
}

// ---------------- pooling + classifier: block per graph, no atomics ---------
__global__ void k_pool2(const float* __restrict__ h, const float* __restrict__ Wc,
                        const float* __restrict__ bc, const int* __restrict__ rp_g,
                        float* __restrict__ out){
    __shared__ float ws[4];
    int g = blockIdx.x, t = threadIdx.x;
    long beg = (long)rp_g[g]*HH, end = (long)rp_g[g+1]*HH;
    float s = 0.f;
    for (long i = beg + t; i < end; i += 256) s += h[i]*Wc[(int)(i & 127)];
    int lane = t & 63, w = t >> 6;
#pragma unroll
    for (int off = 32; off > 0; off >>= 1) s += __shfl_down(s, off);
    if (lane == 0) ws[w] = s;
    __syncthreads();
    if (t == 0) out[g] = bc[0] + ws[0] + ws[1] + ws[2] + ws[3];
}

extern "C" void kernel_launch(void* const* d_in, const int* in_sizes, int n_in,
                              void* d_out, int out_size, void* d_ws, size_t ws_size,
                              hipStream_t stream){
    const float* x     = (const float*)d_in[0];
    const int*   ei    = (const int*)d_in[1];
    const int*   batch = (const int*)d_in[2];
    const float* W1_0  = (const float*)d_in[3];
    const float* b1_0  = (const float*)d_in[4];
    const float* g_0   = (const float*)d_in[5];
    const float* be_0  = (const float*)d_in[6];
    const float* m_0   = (const float*)d_in[7];
    const float* v_0   = (const float*)d_in[8];
    const float* W2_0  = (const float*)d_in[9];
    const float* b2_0  = (const float*)d_in[10];
    const float* W1s   = (const float*)d_in[11];
    const float* b1s   = (const float*)d_in[12];
    const float* gs    = (const float*)d_in[13];
    const float* bes   = (const float*)d_in[14];
    const float* ms    = (const float*)d_in[15];
    const float* vs    = (const float*)d_in[16];
    const float* W2s   = (const float*)d_in[17];
    const float* b2s   = (const float*)d_in[18];
    const float* Wc    = (const float*)d_in[19];
    const float* bc    = (const float*)d_in[20];

    float* P0 = (float*)d_ws;
    float* P1 = P0 + (size_t)NPAD*HH;
    int* rp    = (int*)(P1 + (size_t)NPAD*HH);
    int* fill  = rp + (NN + 1);
    int* ssrc  = fill + NN;
    int* bsums = ssrc + EE;
    int* rp_g  = bsums + 128;
    size_t wp_off = (size_t)(rp_g + (GG + 1) - (int*)d_ws);
    wp_off = (wp_off + 3) & ~(size_t)3;
    short* Wp = (short*)((int*)d_ws + wp_off);

    const int* src = ei;
    const int* dst = ei + EE;

    // --- init (zero fill + rp_g bounds + weight pre-swizzle, one kernel) ---
    k_init<<<(9*16384+255)/256, 256, 0, stream>>>(batch, fill, rp_g,
                                                  W2_0, W1s, W2s, Wp);

    // --- CSR build ---
    k_hist<<<(EE+255)/256, 256, 0, stream>>>(dst, fill);
    k_scan1<<<98, 256, 0, stream>>>(fill, rp, bsums, NN);
    k_scan2<<<1, 128, 0, stream>>>(bsums, 98);
    k_scan3<<<(NN+255)/256, 256, 0, stream>>>(rp, bsums, fill, NN);
    k_place<<<(EE+255)/256, 256, 0, stream>>>(src, dst, fill, ssrc);

    // --- layer 0: agg3 -> fused mlp0+GEMM(W2_0) ---
    k_agg3<<<(NN+255)/256, 256, 0, stream>>>(x, rp, ssrc, P1);
    k_layer0<<<NBLK2, 256, 0, stream>>>(P1, Wp, W1_0, b1_0, g_0, be_0, m_0, v_0,
                                        b2_0, P0);

    // --- layers 1..4: one fused barrier-free kernel per layer ---
    float* cur = P0; float* oth = P1;
    for (int l = 0; l < 4; l++){
        k_layer<<<NBLK2, 256, 0, stream>>>(cur, rp, ssrc,
                                           Wp + (size_t)(1+l)*32768,
                                           Wp + (size_t)(5+l)*32768,
                                           b1s + l*HH, gs + l*HH, bes + l*HH,
                                           ms + l*HH, vs + l*HH, b2s + l*HH,
                                           oth);
        float* tmp = cur; cur = oth; oth = tmp;
    }

    // --- pooling + classifier (no atomics) ---
    k_pool2<<<GG, 256, 0, stream>>>(cur, Wc, bc, rp_g, (float*)d_out);
}